// Round 1
// baseline (26412.534 us; speedup 1.0000x reference)
//
#include <hip/hip_runtime.h>
#include <hip/hip_bf16.h>
#include <math.h>

#define BB 8
#define EE 768
#define HH 12
#define LL 12
#define DD 64
#define MLPD 3072
#define NN 197
#define NPATCH 196
#define NCLS 1000
#define NROWS (BB*NN)        // 1576
#define PROWS (BB*NPATCH)    // 1568
#define SCALE 0.125f

// ---------------- epilogue modes ----------------
#define MODE_PLAIN 0
#define MODE_ELU1  1
#define MODE_GELU  2
#define MODE_RES   3

// ---------------- generic GEMM: C = A[M,K] @ W[Nc,K]^T + bias ----------------
// 64x64 tile, 256 threads, 4x4 per thread.
__global__ __launch_bounds__(256) void gemm_kernel(
    const float* __restrict__ A, const float* __restrict__ W,
    const float* __restrict__ bias, float* __restrict__ C,
    int M, int Nc, int K, int mode,
    const float* __restrict__ gamma, const float* __restrict__ resid)
{
    __shared__ float As[16][64];
    __shared__ float Bs[16][64];
    const int tid = threadIdx.x;
    const int tm = tid >> 4;       // 0..15
    const int tn = tid & 15;       // 0..15
    const int m0 = blockIdx.y * 64;
    const int n0 = blockIdx.x * 64;

    float acc[4][4] = {};

    for (int k0 = 0; k0 < K; k0 += 16) {
#pragma unroll
        for (int i = 0; i < 4; i++) {
            int idx = tid + i * 256;
            int r = idx >> 4;      // 0..63
            int c = idx & 15;      // 0..15
            int gm = m0 + r;
            As[c][r] = (gm < M) ? A[(size_t)gm * K + k0 + c] : 0.f;
            int gn = n0 + r;
            Bs[c][r] = (gn < Nc) ? W[(size_t)gn * K + k0 + c] : 0.f;
        }
        __syncthreads();
#pragma unroll
        for (int kk = 0; kk < 16; kk++) {
            float a[4], b[4];
#pragma unroll
            for (int i = 0; i < 4; i++) a[i] = As[kk][tm * 4 + i];
#pragma unroll
            for (int j = 0; j < 4; j++) b[j] = Bs[kk][tn * 4 + j];
#pragma unroll
            for (int i = 0; i < 4; i++)
#pragma unroll
                for (int j = 0; j < 4; j++)
                    acc[i][j] += a[i] * b[j];
        }
        __syncthreads();
    }

#pragma unroll
    for (int i = 0; i < 4; i++) {
        int gm = m0 + tm * 4 + i;
        if (gm >= M) continue;
#pragma unroll
        for (int j = 0; j < 4; j++) {
            int gn = n0 + tn * 4 + j;
            if (gn >= Nc) continue;
            float v = acc[i][j] + (bias ? bias[gn] : 0.f);
            size_t o = (size_t)gm * Nc + gn;
            if (mode == MODE_ELU1) {
                v = (v > 0.f) ? (v + 1.f) : expf(v);
            } else if (mode == MODE_GELU) {
                v = 0.5f * v * (1.f + erff(v * 0.70710678118654752f));
            } else if (mode == MODE_RES) {
                v = resid[o] + gamma[gn] * v;
            }
            C[o] = v;
        }
    }
}

// ---------------- im2col for 16x16 stride-16 patch conv ----------------
__global__ __launch_bounds__(256) void im2col_kernel(
    const float* __restrict__ x, float* __restrict__ col)
{
    int idx = blockIdx.x * 256 + threadIdx.x;
    if (idx >= PROWS * EE) return;
    int c = idx % EE;          // 0..767 = ch*256 + i*16 + j
    int r = idx / EE;          // 0..1567
    int b = r / NPATCH;
    int p = r % NPATCH;
    int ph = p / 14, pw = p % 14;
    int ch = c >> 8;
    int rem = c & 255;
    int i = rem >> 4, j = rem & 15;
    col[idx] = x[(((size_t)b * 3 + ch) * 224 + (ph * 16 + i)) * 224 + (pw * 16 + j)];
}

// ---------------- assemble tokens: cls + patches ----------------
__global__ __launch_bounds__(256) void assemble_kernel(
    const float* __restrict__ tm, const float* __restrict__ tc,
    const float* __restrict__ cls, const float* __restrict__ ccls,
    float* __restrict__ xm, float* __restrict__ xc)
{
    int idx = blockIdx.x * 256 + threadIdx.x;
    if (idx >= NROWS * EE) return;
    int e = idx % EE;
    int r = idx / EE;
    int b = r / NN, n = r % NN;
    if (n == 0) {
        xm[idx] = cls[e];
        xc[idx] = ccls[e];
    } else {
        size_t s = ((size_t)(b * NPATCH + n - 1)) * EE + e;
        xm[idx] = tm[s];
        xc[idx] = tc[s];
    }
}

// ---------------- LayerNorm over last dim (768) ----------------
__global__ __launch_bounds__(256) void ln_kernel(
    const float* __restrict__ x, float* __restrict__ y,
    const float* __restrict__ g, const float* __restrict__ bb)
{
    int row = blockIdx.x;
    int tid = threadIdx.x;
    __shared__ float red[256];
    const float* xr = x + (size_t)row * EE;
    float v0 = xr[tid], v1 = xr[tid + 256], v2 = xr[tid + 512];
    red[tid] = v0 + v1 + v2;
    __syncthreads();
    for (int s = 128; s > 0; s >>= 1) { if (tid < s) red[tid] += red[tid + s]; __syncthreads(); }
    float mu = red[0] * (1.f / 768.f);
    __syncthreads();
    float d0 = v0 - mu, d1 = v1 - mu, d2 = v2 - mu;
    red[tid] = d0 * d0 + d1 * d1 + d2 * d2;
    __syncthreads();
    for (int s = 128; s > 0; s >>= 1) { if (tid < s) red[tid] += red[tid + s]; __syncthreads(); }
    float rstd = rsqrtf(red[0] * (1.f / 768.f) + 1e-5f);
    float* yr = y + (size_t)row * EE;
    yr[tid]       = d0 * rstd * g[tid]       + bb[tid];
    yr[tid + 256] = d1 * rstd * g[tid + 256] + bb[tid + 256];
    yr[tid + 512] = d2 * rstd * g[tid + 512] + bb[tid + 512];
}

// ---------------- build concat qkv biases ----------------
__global__ __launch_bounds__(256) void qkvbias_kernel(
    const float* __restrict__ qb, const float* __restrict__ vb,
    const float* __restrict__ cqb, const float* __restrict__ cvb,
    float* __restrict__ bm, float* __restrict__ bc)
{
    int j = blockIdx.x * 256 + threadIdx.x;
    if (j >= 3 * EE) return;
    float m, c;
    if (j < EE)       { m = qb[j];         c = cqb[j]; }
    else if (j < 2*EE){ m = 0.f;           c = 0.f; }
    else              { m = vb[j - 2*EE];  c = cvb[j - 2*EE]; }
    bm[j] = m;
    bc[j] = c;
}

// ---------------- Wasserstein + sigmoid + softmax(+relpos) ----------------
// block per (n, b*H+h); 256 threads; thread m computes one attn element.
__global__ __launch_bounds__(256) void attn_kernel(
    const float* __restrict__ qkv, const float* __restrict__ cqkv,
    const float* __restrict__ rpb, float* __restrict__ attn)
{
    int n = blockIdx.x;
    int bh = blockIdx.y;
    int b = bh / HH, h = bh % HH;
    int tid = threadIdx.x;
    __shared__ float qs[64], sq[64];
    __shared__ float scal[2];
    __shared__ float red[256];

    size_t qbase = ((size_t)(b * NN + n) * 3 + 0) * EE + h * DD;
    if (tid < 64) {
        float qv = qkv[qbase + tid] * SCALE;
        float cv = cqkv[qbase + tid];
        qs[tid] = qv;
        sq[tid] = sqrtf(fmaxf(cv, 1e-24f));
        red[tid] = qv * qv;
        red[tid + 64] = cv;
    }
    __syncthreads();
    if (tid == 0) {
        float s1 = 0.f, s2 = 0.f;
        for (int d = 0; d < 64; d++) { s1 += red[d]; s2 += red[d + 64]; }
        scal[0] = s1; scal[1] = s2;
    }
    __syncthreads();

    float logit = -INFINITY;
    int m = tid;
    if (m < NN) {
        size_t kbase = ((size_t)(b * NN + m) * 3 + 1) * EE + h * DD;
        float dm = 0.f, sk2 = 0.f, dc = 0.f, sck = 0.f;
#pragma unroll 8
        for (int d = 0; d < 64; d++) {
            float kv = qkv[kbase + d];
            float ckv = cqkv[kbase + d];
            dm += qs[d] * kv;
            sk2 += kv * kv;
            dc += sq[d] * sqrtf(fmaxf(ckv, 1e-24f));
            sck += ckv;
        }
        float mt = -2.f * dm + scal[0] + sk2;
        float ct = -2.f * dc + scal[1] + sck;
        float z = -(mt + ct) + 1e-24f;
        float s = 1.f / (1.f + expf(-z));
        logit = s + rpb[((size_t)h * NN + n) * NN + m];
    }
    __syncthreads();
    red[tid] = logit;
    __syncthreads();
    for (int s = 128; s > 0; s >>= 1) { if (tid < s) red[tid] = fmaxf(red[tid], red[tid + s]); __syncthreads(); }
    float mx = red[0];
    __syncthreads();
    float ex = (m < NN) ? expf(logit - mx) : 0.f;
    red[tid] = ex;
    __syncthreads();
    for (int s = 128; s > 0; s >>= 1) { if (tid < s) red[tid] += red[tid + s]; __syncthreads(); }
    float denom = red[0];
    if (m < NN) attn[((size_t)bh * NN + n) * NN + m] = ex / denom;
}

// ---------------- ctx: attn @ V and attn^2 @ CV ----------------
__global__ __launch_bounds__(64) void ctx_kernel(
    const float* __restrict__ attn, const float* __restrict__ qkv,
    const float* __restrict__ cqkv, float* __restrict__ ctxm, float* __restrict__ ctxc)
{
    int n = blockIdx.x;
    int bh = blockIdx.y;
    int b = bh / HH, h = bh % HH;
    int d = threadIdx.x;
    const float* arow = attn + ((size_t)bh * NN + n) * NN;
    float am = 0.f, ac = 0.f;
    for (int m = 0; m < NN; m++) {
        float a = arow[m];
        size_t vbase = ((size_t)(b * NN + m) * 3 + 2) * EE + h * DD;
        am += a * qkv[vbase + d];
        ac += a * a * cqkv[vbase + d];
    }
    size_t o = (size_t)(b * NN + n) * EE + h * DD + d;
    ctxm[o] = am;
    ctxc[o] = ac;
}

// ---------------- mean-pool patch tokens + LN ----------------
__global__ __launch_bounds__(256) void pool_ln_kernel(
    const float* __restrict__ xm, float* __restrict__ out,
    const float* __restrict__ g, const float* __restrict__ bb)
{
    int b = blockIdx.x;
    int tid = threadIdx.x;
    __shared__ float red[256];
    float p[3];
#pragma unroll
    for (int i = 0; i < 3; i++) {
        int e = tid + i * 256;
        float s = 0.f;
        for (int n = 1; n < NN; n++) s += xm[((size_t)(b * NN + n)) * EE + e];
        p[i] = s * (1.f / 196.f);
    }
    red[tid] = p[0] + p[1] + p[2];
    __syncthreads();
    for (int s = 128; s > 0; s >>= 1) { if (tid < s) red[tid] += red[tid + s]; __syncthreads(); }
    float mu = red[0] * (1.f / 768.f);
    __syncthreads();
    float d0 = p[0] - mu, d1 = p[1] - mu, d2 = p[2] - mu;
    red[tid] = d0 * d0 + d1 * d1 + d2 * d2;
    __syncthreads();
    for (int s = 128; s > 0; s >>= 1) { if (tid < s) red[tid] += red[tid + s]; __syncthreads(); }
    float rstd = rsqrtf(red[0] * (1.f / 768.f) + 1e-5f);
    out[(size_t)b * EE + tid]       = d0 * rstd * g[tid]       + bb[tid];
    out[(size_t)b * EE + tid + 256] = d1 * rstd * g[tid + 256] + bb[tid + 256];
    out[(size_t)b * EE + tid + 512] = d2 * rstd * g[tid + 512] + bb[tid + 512];
}

// =========================================================================
extern "C" void kernel_launch(void* const* d_in, const int* in_sizes, int n_in,
                              void* d_out, int out_size, void* d_ws, size_t ws_size,
                              hipStream_t stream)
{
    const float* x        = (const float*)d_in[0];
    const float* rpb      = (const float*)d_in[1];
    const float* patch_w  = (const float*)d_in[2];
    const float* patch_b  = (const float*)d_in[3];
    const float* cpatch_w = (const float*)d_in[4];
    const float* cpatch_b = (const float*)d_in[5];
    const float* cls_tok  = (const float*)d_in[6];
    const float* ccls_tok = (const float*)d_in[7];
    const float* norm1_g  = (const float*)d_in[8];
    const float* norm1_b  = (const float*)d_in[9];
    const float* qkv_w    = (const float*)d_in[10];
    const float* q_bias   = (const float*)d_in[11];
    const float* v_bias   = (const float*)d_in[12];
    const float* cq_bias  = (const float*)d_in[13];
    const float* cv_bias  = (const float*)d_in[14];
    const float* proj_w   = (const float*)d_in[15];
    const float* proj_b   = (const float*)d_in[16];
    const float* cproj_w  = (const float*)d_in[17];
    const float* cproj_b  = (const float*)d_in[18];
    const float* gamma1   = (const float*)d_in[19];
    const float* gamma2   = (const float*)d_in[20];
    const float* norm2_g  = (const float*)d_in[21];
    const float* norm2_b  = (const float*)d_in[22];
    const float* fc1_w    = (const float*)d_in[23];
    const float* fc1_b    = (const float*)d_in[24];
    const float* fc2_w    = (const float*)d_in[25];
    const float* fc2_b    = (const float*)d_in[26];
    const float* fcn_g    = (const float*)d_in[27];
    const float* fcn_b    = (const float*)d_in[28];
    const float* head_w   = (const float*)d_in[29];
    const float* head_b   = (const float*)d_in[30];
    float* out = (float*)d_out;

    // workspace layout (floats)
    size_t off = 0;
    float* base = (float*)d_ws;
    auto alloc = [&](size_t n) { float* p = base + off; off += n; return p; };
    float* xm    = alloc((size_t)NROWS * EE);
    float* xc    = alloc((size_t)NROWS * EE);
    float* xn    = alloc((size_t)NROWS * EE);
    float* qkv   = alloc((size_t)NROWS * 3 * EE);
    float* cqkv  = alloc((size_t)NROWS * 3 * EE);
    float* attn  = alloc((size_t)BB * HH * NN * NN);
    float* ctxm  = alloc((size_t)NROWS * EE);
    float* ctxc  = alloc((size_t)NROWS * EE);
    float* hbuf  = alloc((size_t)NROWS * MLPD);
    float* col   = alloc((size_t)PROWS * EE);
    float* biasq = alloc(3 * EE);
    float* biasc = alloc(3 * EE);
    float* pooled= alloc((size_t)BB * EE);

    dim3 t256(256);

    // ---- patch embed (im2col + 2 GEMMs) ----
    im2col_kernel<<<dim3((PROWS * EE + 255) / 256), t256, 0, stream>>>(x, col);
    {
        dim3 grid(EE / 64, (PROWS + 63) / 64);
        gemm_kernel<<<grid, t256, 0, stream>>>(col, patch_w, patch_b, ctxm,
                                               PROWS, EE, EE, MODE_PLAIN, nullptr, nullptr);
        gemm_kernel<<<grid, t256, 0, stream>>>(col, cpatch_w, cpatch_b, ctxc,
                                               PROWS, EE, EE, MODE_PLAIN, nullptr, nullptr);
    }
    assemble_kernel<<<dim3((NROWS * EE + 255) / 256), t256, 0, stream>>>(
        ctxm, ctxc, cls_tok, ccls_tok, xm, xc);

    dim3 gridQKV(3 * EE / 64, (NROWS + 63) / 64);
    dim3 gridE(EE / 64, (NROWS + 63) / 64);
    dim3 gridMLP(MLPD / 64, (NROWS + 63) / 64);
    dim3 gridAttn(NN, BB * HH);

    for (int l = 0; l < LL; l++) {
        const float* qw  = qkv_w  + (size_t)l * 3 * EE * EE;
        const float* pw  = proj_w + (size_t)l * EE * EE;
        const float* cpw = cproj_w+ (size_t)l * EE * EE;
        const float* f1w = fc1_w  + (size_t)l * MLPD * EE;
        const float* f2w = fc2_w  + (size_t)l * EE * MLPD;

        qkvbias_kernel<<<dim3(9), t256, 0, stream>>>(
            q_bias + l * EE, v_bias + l * EE, cq_bias + l * EE, cv_bias + l * EE,
            biasq, biasc);

        // mean path norm1 + qkv
        ln_kernel<<<dim3(NROWS), t256, 0, stream>>>(xm, xn, norm1_g + l * EE, norm1_b + l * EE);
        gemm_kernel<<<gridQKV, t256, 0, stream>>>(xn, qw, biasq, qkv,
                                                  NROWS, 3 * EE, EE, MODE_PLAIN, nullptr, nullptr);
        // cov path norm1 + qkv (elu+1)
        ln_kernel<<<dim3(NROWS), t256, 0, stream>>>(xc, xn, norm1_g + l * EE, norm1_b + l * EE);
        gemm_kernel<<<gridQKV, t256, 0, stream>>>(xn, qw, biasc, cqkv,
                                                  NROWS, 3 * EE, EE, MODE_ELU1, nullptr, nullptr);

        // attention
        attn_kernel<<<gridAttn, t256, 0, stream>>>(qkv, cqkv, rpb, attn);
        ctx_kernel<<<gridAttn, dim3(64), 0, stream>>>(attn, qkv, cqkv, ctxm, ctxc);

        // proj + residual
        gemm_kernel<<<gridE, t256, 0, stream>>>(ctxm, pw, proj_b + l * EE, xm,
                                                NROWS, EE, EE, MODE_RES, gamma1 + l * EE, xm);
        gemm_kernel<<<gridE, t256, 0, stream>>>(ctxc, cpw, cproj_b + l * EE, xc,
                                                NROWS, EE, EE, MODE_RES, gamma1 + l * EE, xc);

        // MLP (mean path)
        ln_kernel<<<dim3(NROWS), t256, 0, stream>>>(xm, xn, norm2_g + l * EE, norm2_b + l * EE);
        gemm_kernel<<<gridMLP, t256, 0, stream>>>(xn, f1w, fc1_b + l * MLPD, hbuf,
                                                  NROWS, MLPD, EE, MODE_GELU, nullptr, nullptr);
        gemm_kernel<<<gridE, t256, 0, stream>>>(hbuf, f2w, fc2_b + l * EE, xm,
                                                NROWS, EE, MLPD, MODE_RES, gamma2 + l * EE, xm);

        // MLP (cov path)
        ln_kernel<<<dim3(NROWS), t256, 0, stream>>>(xc, xn, norm2_g + l * EE, norm2_b + l * EE);
        gemm_kernel<<<gridMLP, t256, 0, stream>>>(xn, f1w, fc1_b + l * MLPD, hbuf,
                                                  NROWS, MLPD, EE, MODE_GELU, nullptr, nullptr);
        gemm_kernel<<<gridE, t256, 0, stream>>>(hbuf, f2w, fc2_b + l * EE, xc,
                                                NROWS, EE, MLPD, MODE_RES, gamma2 + l * EE, xc);
    }

    // ---- head ----
    pool_ln_kernel<<<dim3(BB), t256, 0, stream>>>(xm, pooled, fcn_g, fcn_b);
    {
        dim3 grid((NCLS + 63) / 64, (BB + 63) / 64);
        gemm_kernel<<<grid, t256, 0, stream>>>(pooled, head_w, head_b, out,
                                               BB, NCLS, EE, MODE_PLAIN, nullptr, nullptr);
    }
}

// Round 2
// 9707.695 us; speedup vs baseline: 2.7208x; 2.7208x over previous
//
#include <hip/hip_runtime.h>
#include <hip/hip_bf16.h>
#include <math.h>

#define BB 8
#define EE 768
#define HH 12
#define LL 12
#define DD 64
#define MLPD 3072
#define NN 197
#define NPATCH 196
#define NCLS 1000
#define NROWS (BB*NN)        // 1576
#define PROWS (BB*NPATCH)    // 1568
#define MPAD 1664            // 13 * 128
#define SCALE 0.125f

// epilogue modes for mfma gemm
#define MODE_F32   0   // plain, fp32 out
#define MODE_ELU1F 1   // elu+1, fp32 out
#define MODE_GELUB 2   // exact gelu, bf16 out
#define MODE_RESF  3   // resid + gamma*v, fp32 out

typedef __attribute__((ext_vector_type(8))) short bf16x8;
typedef __attribute__((ext_vector_type(4))) float f32x4;

__device__ __forceinline__ unsigned short f2b(float f) {
    union { __hip_bfloat16 h; unsigned short u; } x;
    x.h = __float2bfloat16(f);
    return x.u;
}

// =============== MFMA bf16 GEMM: C = A[Mpad,K](bf16) @ W[Nc,K](bf16)^T + bias ===============
// 128x128 tile, BK=32, 256 threads = 4 waves in 2x2, each wave 64x64 via 4x4 of 16x16x32.
__global__ __launch_bounds__(256) void mfma_gemm(
    const unsigned short* __restrict__ A, const unsigned short* __restrict__ W,
    const float* __restrict__ bias, int K, int Nc, int mode,
    const float* __restrict__ gamma, const float* __restrict__ resid,
    float* __restrict__ Cf, unsigned short* __restrict__ Cb)
{
    __shared__ unsigned short lA[128 * 32];
    __shared__ unsigned short lB[128 * 32];
    const int tid  = threadIdx.x;
    const int lane = tid & 63;
    const int wave = tid >> 6;
    const int wm = wave >> 1, wn = wave & 1;
    const int m0 = blockIdx.y * 128;
    const int n0 = blockIdx.x * 128;

    const int srow  = lane >> 2;        // 0..15 within a 16-row chunk
    const int skoff = (lane & 3) * 8;   // bf16 element offset in k

    f32x4 acc[4][4];
#pragma unroll
    for (int i = 0; i < 4; i++)
#pragma unroll
        for (int j = 0; j < 4; j++) acc[i][j] = (f32x4){0.f, 0.f, 0.f, 0.f};

    const int fr = lane & 15;
    const int fk = (lane >> 4) * 8;

    for (int k0 = 0; k0 < K; k0 += 32) {
#pragma unroll
        for (int i = 0; i < 2; i++) {
            int chunk = wave * 2 + i;          // 0..7, 16 rows each
            int row = chunk * 16 + srow;
            const unsigned short* ga = A + (size_t)(m0 + row) * K + k0 + skoff;
            __builtin_amdgcn_global_load_lds(
                (const __attribute__((address_space(1))) unsigned int*)ga,
                (__attribute__((address_space(3))) unsigned int*)(lA + chunk * 512),
                16, 0, 0);
            const unsigned short* gb = W + (size_t)(n0 + row) * K + k0 + skoff;
            __builtin_amdgcn_global_load_lds(
                (const __attribute__((address_space(1))) unsigned int*)gb,
                (__attribute__((address_space(3))) unsigned int*)(lB + chunk * 512),
                16, 0, 0);
        }
        __syncthreads();

        bf16x8 a[4], b[4];
#pragma unroll
        for (int t = 0; t < 4; t++) {
            a[t] = *(const bf16x8*)(lA + (wm * 64 + t * 16 + fr) * 32 + fk);
            b[t] = *(const bf16x8*)(lB + (wn * 64 + t * 16 + fr) * 32 + fk);
        }
#pragma unroll
        for (int i = 0; i < 4; i++)
#pragma unroll
            for (int j = 0; j < 4; j++)
                acc[i][j] = __builtin_amdgcn_mfma_f32_16x16x32_bf16(a[i], b[j], acc[i][j], 0, 0, 0);
        __syncthreads();
    }

    const int crow0 = m0 + wm * 64;
    const int ccol0 = n0 + wn * 64;
    const int lr = (lane >> 4) * 4;
    const int lc = lane & 15;
#pragma unroll
    for (int i = 0; i < 4; i++) {
#pragma unroll
        for (int j = 0; j < 4; j++) {
            int col = ccol0 + j * 16 + lc;
            float bv = bias ? bias[col] : 0.f;
#pragma unroll
            for (int r = 0; r < 4; r++) {
                int row = crow0 + i * 16 + lr + r;
                float v = acc[i][j][r] + bv;
                size_t o = (size_t)row * Nc + col;
                if (mode == MODE_ELU1F) {
                    Cf[o] = (v > 0.f) ? (v + 1.f) : expf(v);
                } else if (mode == MODE_GELUB) {
                    v = 0.5f * v * (1.f + erff(v * 0.70710678118654752f));
                    Cb[o] = f2b(v);
                } else if (mode == MODE_RESF) {
                    Cf[o] = resid[o] + gamma[col] * v;
                } else {
                    Cf[o] = v;
                }
            }
        }
    }
}

// =============== fp32 GEMM (head only): C = A[M,K] @ W[Nc,K]^T + bias ===============
__global__ __launch_bounds__(256) void gemm_kernel(
    const float* __restrict__ A, const float* __restrict__ W,
    const float* __restrict__ bias, float* __restrict__ C,
    int M, int Nc, int K)
{
    __shared__ float As[16][64];
    __shared__ float Bs[16][64];
    const int tid = threadIdx.x;
    const int tm = tid >> 4;
    const int tn = tid & 15;
    const int m0 = blockIdx.y * 64;
    const int n0 = blockIdx.x * 64;

    float acc[4][4] = {};
    for (int k0 = 0; k0 < K; k0 += 16) {
#pragma unroll
        for (int i = 0; i < 4; i++) {
            int idx = tid + i * 256;
            int r = idx >> 4;
            int c = idx & 15;
            int gm = m0 + r;
            As[c][r] = (gm < M) ? A[(size_t)gm * K + k0 + c] : 0.f;
            int gn = n0 + r;
            Bs[c][r] = (gn < Nc) ? W[(size_t)gn * K + k0 + c] : 0.f;
        }
        __syncthreads();
#pragma unroll
        for (int kk = 0; kk < 16; kk++) {
            float a[4], b[4];
#pragma unroll
            for (int i = 0; i < 4; i++) a[i] = As[kk][tm * 4 + i];
#pragma unroll
            for (int j = 0; j < 4; j++) b[j] = Bs[kk][tn * 4 + j];
#pragma unroll
            for (int i = 0; i < 4; i++)
#pragma unroll
                for (int j = 0; j < 4; j++)
                    acc[i][j] += a[i] * b[j];
        }
        __syncthreads();
    }
#pragma unroll
    for (int i = 0; i < 4; i++) {
        int gm = m0 + tm * 4 + i;
        if (gm >= M) continue;
#pragma unroll
        for (int j = 0; j < 4; j++) {
            int gn = n0 + tn * 4 + j;
            if (gn >= Nc) continue;
            C[(size_t)gm * Nc + gn] = acc[i][j] + (bias ? bias[gn] : 0.f);
        }
    }
}

// =============== fp32 -> bf16 conversion ===============
__global__ __launch_bounds__(256) void cvt_kernel(
    const float* __restrict__ src, unsigned short* __restrict__ dst, int n)
{
    int i = (blockIdx.x * 256 + threadIdx.x) * 4;
    if (i >= n) return;
    float4 f = *(const float4*)(src + i);
    ushort4 u;
    u.x = f2b(f.x); u.y = f2b(f.y); u.z = f2b(f.z); u.w = f2b(f.w);
    *(ushort4*)(dst + i) = u;
}

// per-layer fused weight conversion into wbuf
#define W_QKV   0
#define W_PROJ  1769472
#define W_CPROJ 2359296
#define W_FC1   2949120
#define W_FC2   5308416
#define W_TOTAL 7667712

__global__ __launch_bounds__(256) void cvt_layer_kernel(
    const float* __restrict__ qkvw, const float* __restrict__ pw,
    const float* __restrict__ cpw, const float* __restrict__ f1,
    const float* __restrict__ f2, unsigned short* __restrict__ dst)
{
    int i = (blockIdx.x * 256 + threadIdx.x) * 4;
    if (i >= W_TOTAL) return;
    const float* s; int off;
    if (i < W_PROJ)        { s = qkvw; off = W_QKV; }
    else if (i < W_CPROJ)  { s = pw;   off = W_PROJ; }
    else if (i < W_FC1)    { s = cpw;  off = W_CPROJ; }
    else if (i < W_FC2)    { s = f1;   off = W_FC1; }
    else                   { s = f2;   off = W_FC2; }
    float4 f = *(const float4*)(s + (i - off));
    ushort4 u;
    u.x = f2b(f.x); u.y = f2b(f.y); u.z = f2b(f.z); u.w = f2b(f.w);
    *(ushort4*)(dst + i) = u;
}

// =============== im2col (bf16 out) ===============
__global__ __launch_bounds__(256) void im2col_kernel(
    const float* __restrict__ x, unsigned short* __restrict__ col)
{
    int idx = blockIdx.x * 256 + threadIdx.x;
    if (idx >= PROWS * EE) return;
    int c = idx % EE;
    int r = idx / EE;
    int b = r / NPATCH;
    int p = r % NPATCH;
    int ph = p / 14, pw = p % 14;
    int ch = c >> 8;
    int rem = c & 255;
    int i = rem >> 4, j = rem & 15;
    col[idx] = f2b(x[(((size_t)b * 3 + ch) * 224 + (ph * 16 + i)) * 224 + (pw * 16 + j)]);
}

// =============== assemble tokens: cls + patches (fp32) ===============
__global__ __launch_bounds__(256) void assemble_kernel(
    const float* __restrict__ tm, const float* __restrict__ tc,
    const float* __restrict__ cls, const float* __restrict__ ccls,
    float* __restrict__ xm, float* __restrict__ xc)
{
    int idx = blockIdx.x * 256 + threadIdx.x;
    if (idx >= NROWS * EE) return;
    int e = idx % EE;
    int r = idx / EE;
    int b = r / NN, n = r % NN;
    if (n == 0) {
        xm[idx] = cls[e];
        xc[idx] = ccls[e];
    } else {
        size_t s = ((size_t)(b * NPATCH + n - 1)) * EE + e;
        xm[idx] = tm[s];
        xc[idx] = tc[s];
    }
}

// =============== LayerNorm (fp32 in, bf16 out) ===============
__global__ __launch_bounds__(256) void ln_kernel(
    const float* __restrict__ x, unsigned short* __restrict__ y,
    const float* __restrict__ g, const float* __restrict__ bb)
{
    int row = blockIdx.x;
    int tid = threadIdx.x;
    __shared__ float red[256];
    const float* xr = x + (size_t)row * EE;
    float v0 = xr[tid], v1 = xr[tid + 256], v2 = xr[tid + 512];
    red[tid] = v0 + v1 + v2;
    __syncthreads();
    for (int s = 128; s > 0; s >>= 1) { if (tid < s) red[tid] += red[tid + s]; __syncthreads(); }
    float mu = red[0] * (1.f / 768.f);
    __syncthreads();
    float d0 = v0 - mu, d1 = v1 - mu, d2 = v2 - mu;
    red[tid] = d0 * d0 + d1 * d1 + d2 * d2;
    __syncthreads();
    for (int s = 128; s > 0; s >>= 1) { if (tid < s) red[tid] += red[tid + s]; __syncthreads(); }
    float rstd = rsqrtf(red[0] * (1.f / 768.f) + 1e-5f);
    unsigned short* yr = y + (size_t)row * EE;
    yr[tid]       = f2b(d0 * rstd * g[tid]       + bb[tid]);
    yr[tid + 256] = f2b(d1 * rstd * g[tid + 256] + bb[tid + 256]);
    yr[tid + 512] = f2b(d2 * rstd * g[tid + 512] + bb[tid + 512]);
}

// =============== concat qkv biases ===============
__global__ __launch_bounds__(256) void qkvbias_kernel(
    const float* __restrict__ qb, const float* __restrict__ vb,
    const float* __restrict__ cqb, const float* __restrict__ cvb,
    float* __restrict__ bm, float* __restrict__ bc)
{
    int j = blockIdx.x * 256 + threadIdx.x;
    if (j >= 3 * EE) return;
    float m, c;
    if (j < EE)        { m = qb[j];        c = cqb[j]; }
    else if (j < 2*EE) { m = 0.f;          c = 0.f; }
    else               { m = vb[j - 2*EE]; c = cvb[j - 2*EE]; }
    bm[j] = m;
    bc[j] = c;
}

// =============== Wasserstein + sigmoid + softmax ===============
__global__ __launch_bounds__(256) void attn_kernel(
    const float* __restrict__ qkv, const float* __restrict__ cqkv,
    const float* __restrict__ rpb, float* __restrict__ attn)
{
    int n = blockIdx.x;
    int bh = blockIdx.y;
    int b = bh / HH, h = bh % HH;
    int tid = threadIdx.x;
    __shared__ float qs[64], sq[64];
    __shared__ float scal[2];
    __shared__ float red[256];

    size_t qbase = ((size_t)(b * NN + n) * 3 + 0) * EE + h * DD;
    if (tid < 64) {
        float qv = qkv[qbase + tid] * SCALE;
        float cv = cqkv[qbase + tid];
        qs[tid] = qv;
        sq[tid] = sqrtf(fmaxf(cv, 1e-24f));
        red[tid] = qv * qv;
        red[tid + 64] = cv;
    }
    __syncthreads();
    if (tid == 0) {
        float s1 = 0.f, s2 = 0.f;
        for (int d = 0; d < 64; d++) { s1 += red[d]; s2 += red[d + 64]; }
        scal[0] = s1; scal[1] = s2;
    }
    __syncthreads();

    float logit = -INFINITY;
    int m = tid;
    if (m < NN) {
        size_t kbase = ((size_t)(b * NN + m) * 3 + 1) * EE + h * DD;
        float dm = 0.f, sk2 = 0.f, dc = 0.f, sck = 0.f;
#pragma unroll 8
        for (int d = 0; d < 64; d++) {
            float kv = qkv[kbase + d];
            float ckv = cqkv[kbase + d];
            dm += qs[d] * kv;
            sk2 += kv * kv;
            dc += sq[d] * sqrtf(fmaxf(ckv, 1e-24f));
            sck += ckv;
        }
        float mt = -2.f * dm + scal[0] + sk2;
        float ct = -2.f * dc + scal[1] + sck;
        float z = -(mt + ct) + 1e-24f;
        float s = 1.f / (1.f + expf(-z));
        logit = s + rpb[((size_t)h * NN + n) * NN + m];
    }
    __syncthreads();
    red[tid] = logit;
    __syncthreads();
    for (int s = 128; s > 0; s >>= 1) { if (tid < s) red[tid] = fmaxf(red[tid], red[tid + s]); __syncthreads(); }
    float mx = red[0];
    __syncthreads();
    float ex = (m < NN) ? expf(logit - mx) : 0.f;
    red[tid] = ex;
    __syncthreads();
    for (int s = 128; s > 0; s >>= 1) { if (tid < s) red[tid] += red[tid + s]; __syncthreads(); }
    float denom = red[0];
    if (m < NN) attn[((size_t)bh * NN + n) * NN + m] = ex / denom;
}

// =============== ctx: attn @ V, attn^2 @ CV (bf16 out) ===============
__global__ __launch_bounds__(64) void ctx_kernel(
    const float* __restrict__ attn, const float* __restrict__ qkv,
    const float* __restrict__ cqkv, unsigned short* __restrict__ ctxm,
    unsigned short* __restrict__ ctxc)
{
    int n = blockIdx.x;
    int bh = blockIdx.y;
    int b = bh / HH, h = bh % HH;
    int d = threadIdx.x;
    const float* arow = attn + ((size_t)bh * NN + n) * NN;
    float am = 0.f, ac = 0.f;
    for (int m = 0; m < NN; m++) {
        float a = arow[m];
        size_t vbase = ((size_t)(b * NN + m) * 3 + 2) * EE + h * DD;
        am += a * qkv[vbase + d];
        ac += a * a * cqkv[vbase + d];
    }
    size_t o = (size_t)(b * NN + n) * EE + h * DD + d;
    ctxm[o] = f2b(am);
    ctxc[o] = f2b(ac);
}

// =============== mean-pool + LN (fp32) ===============
__global__ __launch_bounds__(256) void pool_ln_kernel(
    const float* __restrict__ xm, float* __restrict__ out,
    const float* __restrict__ g, const float* __restrict__ bb)
{
    int b = blockIdx.x;
    int tid = threadIdx.x;
    __shared__ float red[256];
    float p[3];
#pragma unroll
    for (int i = 0; i < 3; i++) {
        int e = tid + i * 256;
        float s = 0.f;
        for (int n = 1; n < NN; n++) s += xm[((size_t)(b * NN + n)) * EE + e];
        p[i] = s * (1.f / 196.f);
    }
    red[tid] = p[0] + p[1] + p[2];
    __syncthreads();
    for (int s = 128; s > 0; s >>= 1) { if (tid < s) red[tid] += red[tid + s]; __syncthreads(); }
    float mu = red[0] * (1.f / 768.f);
    __syncthreads();
    float d0 = p[0] - mu, d1 = p[1] - mu, d2 = p[2] - mu;
    red[tid] = d0 * d0 + d1 * d1 + d2 * d2;
    __syncthreads();
    for (int s = 128; s > 0; s >>= 1) { if (tid < s) red[tid] += red[tid + s]; __syncthreads(); }
    float rstd = rsqrtf(red[0] * (1.f / 768.f) + 1e-5f);
    out[(size_t)b * EE + tid]       = d0 * rstd * g[tid]       + bb[tid];
    out[(size_t)b * EE + tid + 256] = d1 * rstd * g[tid + 256] + bb[tid + 256];
    out[(size_t)b * EE + tid + 512] = d2 * rstd * g[tid + 512] + bb[tid + 512];
}

// =========================================================================
extern "C" void kernel_launch(void* const* d_in, const int* in_sizes, int n_in,
                              void* d_out, int out_size, void* d_ws, size_t ws_size,
                              hipStream_t stream)
{
    const float* x        = (const float*)d_in[0];
    const float* rpb      = (const float*)d_in[1];
    const float* patch_w  = (const float*)d_in[2];
    const float* patch_b  = (const float*)d_in[3];
    const float* cpatch_w = (const float*)d_in[4];
    const float* cpatch_b = (const float*)d_in[5];
    const float* cls_tok  = (const float*)d_in[6];
    const float* ccls_tok = (const float*)d_in[7];
    const float* norm1_g  = (const float*)d_in[8];
    const float* norm1_b  = (const float*)d_in[9];
    const float* qkv_w    = (const float*)d_in[10];
    const float* q_bias   = (const float*)d_in[11];
    const float* v_bias   = (const float*)d_in[12];
    const float* cq_bias  = (const float*)d_in[13];
    const float* cv_bias  = (const float*)d_in[14];
    const float* proj_w   = (const float*)d_in[15];
    const float* proj_b   = (const float*)d_in[16];
    const float* cproj_w  = (const float*)d_in[17];
    const float* cproj_b  = (const float*)d_in[18];
    const float* gamma1   = (const float*)d_in[19];
    const float* gamma2   = (const float*)d_in[20];
    const float* norm2_g  = (const float*)d_in[21];
    const float* norm2_b  = (const float*)d_in[22];
    const float* fc1_w    = (const float*)d_in[23];
    const float* fc1_b    = (const float*)d_in[24];
    const float* fc2_w    = (const float*)d_in[25];
    const float* fc2_b    = (const float*)d_in[26];
    const float* fcn_g    = (const float*)d_in[27];
    const float* fcn_b    = (const float*)d_in[28];
    const float* head_w   = (const float*)d_in[29];
    const float* head_b   = (const float*)d_in[30];
    float* out = (float*)d_out;

    // ---- workspace layout (256B aligned chunks) ----
    char* base = (char*)d_ws;
    size_t off = 0;
    auto alloc = [&](size_t bytes) {
        void* p = base + off;
        off = (off + bytes + 255) & ~(size_t)255;
        return p;
    };
    unsigned short* wbuf  = (unsigned short*)alloc((size_t)W_TOTAL * 2);
    unsigned short* pw_m  = (unsigned short*)alloc((size_t)589824 * 2);
    unsigned short* pw_c  = (unsigned short*)alloc((size_t)589824 * 2);
    float* xm   = (float*)alloc((size_t)MPAD * EE * 4);
    float* xc   = (float*)alloc((size_t)MPAD * EE * 4);
    unsigned short* xn   = (unsigned short*)alloc((size_t)MPAD * EE * 2);
    float* qkv  = (float*)alloc((size_t)MPAD * 3 * EE * 4);
    float* cqkv = (float*)alloc((size_t)MPAD * 3 * EE * 4);
    float* attn = (float*)alloc((size_t)BB * HH * NN * NN * 4);
    unsigned short* ctxm = (unsigned short*)alloc((size_t)MPAD * EE * 2);
    unsigned short* ctxc = (unsigned short*)alloc((size_t)MPAD * EE * 2);
    unsigned short* hbuf = (unsigned short*)alloc((size_t)MPAD * MLPD * 2);
    unsigned short* colb = (unsigned short*)alloc((size_t)MPAD * EE * 2);
    float* biasq  = (float*)alloc(3 * EE * 4);
    float* biasc  = (float*)alloc(3 * EE * 4);
    float* pooled = (float*)alloc((size_t)BB * EE * 4);
    // patch-embed fp32 outputs alias the (not yet used) qkv buffers
    float* tm = qkv;
    float* tc = cqkv;

    dim3 t256(256);

    // ---- patch embed ----
    cvt_kernel<<<dim3(589824 / 4 / 256), t256, 0, stream>>>(patch_w, pw_m, 589824);
    cvt_kernel<<<dim3(589824 / 4 / 256), t256, 0, stream>>>(cpatch_w, pw_c, 589824);
    im2col_kernel<<<dim3((PROWS * EE + 255) / 256), t256, 0, stream>>>(x, colb);
    {
        dim3 grid(EE / 128, MPAD / 128);
        mfma_gemm<<<grid, t256, 0, stream>>>(colb, pw_m, patch_b, EE, EE, MODE_F32,
                                             nullptr, nullptr, tm, nullptr);
        mfma_gemm<<<grid, t256, 0, stream>>>(colb, pw_c, cpatch_b, EE, EE, MODE_F32,
                                             nullptr, nullptr, tc, nullptr);
    }
    assemble_kernel<<<dim3((NROWS * EE + 255) / 256), t256, 0, stream>>>(
        tm, tc, cls_tok, ccls_tok, xm, xc);

    dim3 gridQKV(3 * EE / 128, MPAD / 128);
    dim3 gridE(EE / 128, MPAD / 128);
    dim3 gridMLP(MLPD / 128, MPAD / 128);
    dim3 gridAttn(NN, BB * HH);
    dim3 gridCvtL((W_TOTAL / 4 + 255) / 256);

    for (int l = 0; l < LL; l++) {
        cvt_layer_kernel<<<gridCvtL, t256, 0, stream>>>(
            qkv_w + (size_t)l * 3 * EE * EE, proj_w + (size_t)l * EE * EE,
            cproj_w + (size_t)l * EE * EE, fc1_w + (size_t)l * MLPD * EE,
            fc2_w + (size_t)l * EE * MLPD, wbuf);
        qkvbias_kernel<<<dim3(9), t256, 0, stream>>>(
            q_bias + l * EE, v_bias + l * EE, cq_bias + l * EE, cv_bias + l * EE,
            biasq, biasc);

        // norm1 + qkv (mean), norm1 + qkv elu+1 (cov)
        ln_kernel<<<dim3(NROWS), t256, 0, stream>>>(xm, xn, norm1_g + l * EE, norm1_b + l * EE);
        mfma_gemm<<<gridQKV, t256, 0, stream>>>(xn, wbuf + W_QKV, biasq, EE, 3 * EE,
                                                MODE_F32, nullptr, nullptr, qkv, nullptr);
        ln_kernel<<<dim3(NROWS), t256, 0, stream>>>(xc, xn, norm1_g + l * EE, norm1_b + l * EE);
        mfma_gemm<<<gridQKV, t256, 0, stream>>>(xn, wbuf + W_QKV, biasc, EE, 3 * EE,
                                                MODE_ELU1F, nullptr, nullptr, cqkv, nullptr);

        // attention
        attn_kernel<<<gridAttn, t256, 0, stream>>>(qkv, cqkv, rpb, attn);
        ctx_kernel<<<gridAttn, dim3(64), 0, stream>>>(attn, qkv, cqkv, ctxm, ctxc);

        // proj + residual
        mfma_gemm<<<gridE, t256, 0, stream>>>(ctxm, wbuf + W_PROJ, proj_b + l * EE, EE, EE,
                                              MODE_RESF, gamma1 + l * EE, xm, xm, nullptr);
        mfma_gemm<<<gridE, t256, 0, stream>>>(ctxc, wbuf + W_CPROJ, cproj_b + l * EE, EE, EE,
                                              MODE_RESF, gamma1 + l * EE, xc, xc, nullptr);

        // MLP (mean)
        ln_kernel<<<dim3(NROWS), t256, 0, stream>>>(xm, xn, norm2_g + l * EE, norm2_b + l * EE);
        mfma_gemm<<<gridMLP, t256, 0, stream>>>(xn, wbuf + W_FC1, fc1_b + l * MLPD, EE, MLPD,
                                                MODE_GELUB, nullptr, nullptr, nullptr, hbuf);
        mfma_gemm<<<gridE, t256, 0, stream>>>(hbuf, wbuf + W_FC2, fc2_b + l * EE, MLPD, EE,
                                              MODE_RESF, gamma2 + l * EE, xm, xm, nullptr);

        // MLP (cov)
        ln_kernel<<<dim3(NROWS), t256, 0, stream>>>(xc, xn, norm2_g + l * EE, norm2_b + l * EE);
        mfma_gemm<<<gridMLP, t256, 0, stream>>>(xn, wbuf + W_FC1, fc1_b + l * MLPD, EE, MLPD,
                                                MODE_GELUB, nullptr, nullptr, nullptr, hbuf);
        mfma_gemm<<<gridE, t256, 0, stream>>>(hbuf, wbuf + W_FC2, fc2_b + l * EE, MLPD, EE,
                                              MODE_RESF, gamma2 + l * EE, xc, xc, nullptr);
    }

    // ---- head ----
    pool_ln_kernel<<<dim3(BB), t256, 0, stream>>>(xm, pooled, fcn_g, fcn_b);
    {
        dim3 grid((NCLS + 63) / 64, (BB + 63) / 64);
        gemm_kernel<<<grid, t256, 0, stream>>>(pooled, head_w, head_b, out, BB, NCLS, EE);
    }
}

// Round 3
// 6819.292 us; speedup vs baseline: 3.8732x; 1.4236x over previous
//
#include <hip/hip_runtime.h>
#include <hip/hip_bf16.h>
#include <math.h>

#define BB 8
#define EE 768
#define HH 12
#define LL 12
#define DD 64
#define MLPD 3072
#define NN 197
#define NPATCH 196
#define NCLS 1000
#define NROWS (BB*NN)        // 1576
#define PROWS (BB*NPATCH)    // 1568
#define MPAD 1664            // 13 * 128
#define NBH (BB*HH)          // 96
#define NP224 224
#define NP256 256
#define SCALE 0.125f

// epilogue modes for mfma gemm
#define MODE_F32   0   // plain, fp32 out
#define MODE_ELU1F 1   // elu+1, fp32 out
#define MODE_GELUB 2   // exact gelu, bf16 out
#define MODE_RESF  3   // resid + gamma*v, fp32 out

typedef __attribute__((ext_vector_type(8))) short bf16x8;
typedef __attribute__((ext_vector_type(4))) float f32x4;

__device__ __forceinline__ unsigned short f2b(float f) {
    union { __hip_bfloat16 h; unsigned short u; } x;
    x.h = __float2bfloat16(f);
    return x.u;
}

#define GLD(gptr, lptr) __builtin_amdgcn_global_load_lds( \
    (const __attribute__((address_space(1))) unsigned int*)(gptr), \
    (__attribute__((address_space(3))) unsigned int*)(lptr), 16, 0, 0)

// =============== MFMA bf16 GEMM: C = A[Mpad,K](bf16) @ W[Nc,K](bf16)^T + bias ===============
__global__ __launch_bounds__(256) void mfma_gemm(
    const unsigned short* __restrict__ A, const unsigned short* __restrict__ W,
    const float* __restrict__ bias, int K, int Nc, int mode,
    const float* __restrict__ gamma, const float* __restrict__ resid,
    float* __restrict__ Cf, unsigned short* __restrict__ Cb)
{
    __shared__ unsigned short lA[128 * 32];
    __shared__ unsigned short lB[128 * 32];
    const int tid  = threadIdx.x;
    const int lane = tid & 63;
    const int wave = tid >> 6;
    const int wm = wave >> 1, wn = wave & 1;
    const int m0 = blockIdx.y * 128;
    const int n0 = blockIdx.x * 128;
    const int srow  = lane >> 2;
    const int skoff = (lane & 3) * 8;

    f32x4 acc[4][4];
#pragma unroll
    for (int i = 0; i < 4; i++)
#pragma unroll
        for (int j = 0; j < 4; j++) acc[i][j] = (f32x4){0.f, 0.f, 0.f, 0.f};

    const int fr = lane & 15;
    const int fk = (lane >> 4) * 8;

    for (int k0 = 0; k0 < K; k0 += 32) {
#pragma unroll
        for (int i = 0; i < 2; i++) {
            int chunk = wave * 2 + i;
            int row = chunk * 16 + srow;
            GLD(A + (size_t)(m0 + row) * K + k0 + skoff, lA + chunk * 512);
            GLD(W + (size_t)(n0 + row) * K + k0 + skoff, lB + chunk * 512);
        }
        __syncthreads();
        bf16x8 a[4], b[4];
#pragma unroll
        for (int t = 0; t < 4; t++) {
            a[t] = *(const bf16x8*)(lA + (wm * 64 + t * 16 + fr) * 32 + fk);
            b[t] = *(const bf16x8*)(lB + (wn * 64 + t * 16 + fr) * 32 + fk);
        }
#pragma unroll
        for (int i = 0; i < 4; i++)
#pragma unroll
            for (int j = 0; j < 4; j++)
                acc[i][j] = __builtin_amdgcn_mfma_f32_16x16x32_bf16(a[i], b[j], acc[i][j], 0, 0, 0);
        __syncthreads();
    }

    const int crow0 = m0 + wm * 64;
    const int ccol0 = n0 + wn * 64;
    const int lr = (lane >> 4) * 4;
    const int lc = lane & 15;
#pragma unroll
    for (int i = 0; i < 4; i++) {
#pragma unroll
        for (int j = 0; j < 4; j++) {
            int col = ccol0 + j * 16 + lc;
            float bv = bias ? bias[col] : 0.f;
#pragma unroll
            for (int r = 0; r < 4; r++) {
                int row = crow0 + i * 16 + lr + r;
                float v = acc[i][j][r] + bv;
                size_t o = (size_t)row * Nc + col;
                if (mode == MODE_ELU1F) {
                    Cf[o] = (v > 0.f) ? (v + 1.f) : expf(v);
                } else if (mode == MODE_GELUB) {
                    v = 0.5f * v * (1.f + erff(v * 0.70710678118654752f));
                    Cb[o] = f2b(v);
                } else if (mode == MODE_RESF) {
                    Cf[o] = resid[o] + gamma[col] * v;
                } else {
                    Cf[o] = v;
                }
            }
        }
    }
}

// =============== precompute per-token attention operands ===============
// Aq[bh][256][128]: [q*SCALE | sqrt(cq)]; Bk[bh][256][128]: [k | sqrt(ck)]
// rsum = sum(q^2*S^2)+sum(cq); csum = sum(k^2)+sum(ck)
// vT/cvT[bh][64][224] transposed V / CV
__global__ __launch_bounds__(64) void pre_kernel(
    const float* __restrict__ qkv, const float* __restrict__ cqkv,
    unsigned short* __restrict__ Aq, unsigned short* __restrict__ Bk,
    float* __restrict__ rsum, float* __restrict__ csum,
    unsigned short* __restrict__ vT, unsigned short* __restrict__ cvT)
{
    const int n = blockIdx.x;    // 0..255
    const int bh = blockIdx.y;   // 0..95
    const int b = bh / HH, h = bh % HH;
    const int d = threadIdx.x;   // 0..63
    const size_t arow = ((size_t)bh * NP256 + n) * 128;
    if (n < NN) {
        size_t base = (size_t)(b * NN + n) * 3 * EE + h * DD + d;
        float q  = qkv[base];
        float k  = qkv[base + EE];
        float v  = qkv[base + 2 * EE];
        float cq = cqkv[base];
        float ck = cqkv[base + EE];
        float cv = cqkv[base + 2 * EE];
        float qs = q * SCALE;
        float sqq = sqrtf(fmaxf(cq, 1e-24f));
        float sqk = sqrtf(fmaxf(ck, 1e-24f));
        Aq[arow + d]      = f2b(qs);
        Aq[arow + 64 + d] = f2b(sqq);
        Bk[arow + d]      = f2b(k);
        Bk[arow + 64 + d] = f2b(sqk);
        vT [((size_t)bh * 64 + d) * NP224 + n] = f2b(v);
        cvT[((size_t)bh * 64 + d) * NP224 + n] = f2b(cv);
        float r = qs * qs + cq;
        float c = k * k + ck;
        for (int off = 32; off > 0; off >>= 1) {
            r += __shfl_down(r, off);
            c += __shfl_down(c, off);
        }
        if (d == 0) { rsum[bh * NP256 + n] = r; csum[bh * NP256 + n] = c; }
    } else {
        ((unsigned int*)(Aq + arow))[d] = 0u;
        ((unsigned int*)(Bk + arow))[d] = 0u;
        if (d == 0) { rsum[bh * NP256 + n] = 0.f; csum[bh * NP256 + n] = 0.f; }
        if (n < NP224) {
            vT [((size_t)bh * 64 + d) * NP224 + n] = 0;
            cvT[((size_t)bh * 64 + d) * NP224 + n] = 0;
        }
    }
}

// =============== Wasserstein logits via MFMA + fused sigmoid + rpb ===============
// S[bh][256][256] = sigmoid(2*dot - rsum[n] - csum[m] + 1e-24) + rpb[h][n][m]
__global__ __launch_bounds__(256) void wass_gemm(
    const unsigned short* __restrict__ Aq, const unsigned short* __restrict__ Bk,
    const float* __restrict__ rsum, const float* __restrict__ csum,
    const float* __restrict__ rpb, float* __restrict__ S)
{
    __shared__ unsigned short lA[128 * 32];
    __shared__ unsigned short lB[128 * 32];
    const int tid = threadIdx.x, lane = tid & 63, wave = tid >> 6;
    const int wm = wave >> 1, wn = wave & 1;
    const int bh = blockIdx.z;
    const int h = bh % HH;
    const int m0 = blockIdx.y * 128;   // n tile
    const int n0 = blockIdx.x * 128;   // m tile
    const unsigned short* A = Aq + (size_t)bh * NP256 * 128;
    const unsigned short* B = Bk + (size_t)bh * NP256 * 128;
    const int srow = lane >> 2, skoff = (lane & 3) * 8;
    const int fr = lane & 15, fk = (lane >> 4) * 8;

    f32x4 acc[4][4];
#pragma unroll
    for (int i = 0; i < 4; i++)
#pragma unroll
        for (int j = 0; j < 4; j++) acc[i][j] = (f32x4){0.f, 0.f, 0.f, 0.f};

    for (int k0 = 0; k0 < 128; k0 += 32) {
#pragma unroll
        for (int i = 0; i < 2; i++) {
            int chunk = wave * 2 + i;
            int row = chunk * 16 + srow;
            GLD(A + (size_t)(m0 + row) * 128 + k0 + skoff, lA + chunk * 512);
            GLD(B + (size_t)(n0 + row) * 128 + k0 + skoff, lB + chunk * 512);
        }
        __syncthreads();
        bf16x8 a[4], b[4];
#pragma unroll
        for (int t = 0; t < 4; t++) {
            a[t] = *(const bf16x8*)(lA + (wm * 64 + t * 16 + fr) * 32 + fk);
            b[t] = *(const bf16x8*)(lB + (wn * 64 + t * 16 + fr) * 32 + fk);
        }
#pragma unroll
        for (int i = 0; i < 4; i++)
#pragma unroll
            for (int j = 0; j < 4; j++)
                acc[i][j] = __builtin_amdgcn_mfma_f32_16x16x32_bf16(a[i], b[j], acc[i][j], 0, 0, 0);
        __syncthreads();
    }

    const int lr = (lane >> 4) * 4;
    const int lc = lane & 15;
#pragma unroll
    for (int i = 0; i < 4; i++) {
#pragma unroll
        for (int j = 0; j < 4; j++) {
            int m = n0 + wn * 64 + j * 16 + lc;
            float cs = csum[bh * NP256 + m];
#pragma unroll
            for (int r = 0; r < 4; r++) {
                int n = m0 + wm * 64 + i * 16 + lr + r;
                float z = 2.f * acc[i][j][r] - rsum[bh * NP256 + n] - cs + 1e-24f;
                float s = 1.f / (1.f + expf(-z));
                float rp = (n < NN && m < NN) ? rpb[((size_t)h * NN + n) * NN + m] : 0.f;
                S[((size_t)bh * NP256 + n) * NP256 + m] = s + rp;
            }
        }
    }
}

// =============== softmax over m; emit bf16 attn and attn^2 ===============
__global__ __launch_bounds__(256) void softmax_kernel(
    const float* __restrict__ S, unsigned short* __restrict__ Ab,
    unsigned short* __restrict__ A2b)
{
    const int wave = threadIdx.x >> 6, lane = threadIdx.x & 63;
    const int idx = blockIdx.x * 4 + wave;
    if (idx >= NBH * NN) return;
    const int bh = idx / NN, n = idx % NN;
    const float* row = S + ((size_t)bh * NP256 + n) * NP256;
    float l[4], mx = -1e30f;
#pragma unroll
    for (int j = 0; j < 4; j++) {
        int m = lane + j * 64;
        l[j] = (m < NN) ? row[m] : -1e30f;
        mx = fmaxf(mx, l[j]);
    }
    for (int off = 32; off > 0; off >>= 1) mx = fmaxf(mx, __shfl_xor(mx, off));
    float e[4], sum = 0.f;
#pragma unroll
    for (int j = 0; j < 4; j++) {
        int m = lane + j * 64;
        e[j] = (m < NN) ? expf(l[j] - mx) : 0.f;
        sum += e[j];
    }
    for (int off = 32; off > 0; off >>= 1) sum += __shfl_xor(sum, off);
    float inv = 1.f / sum;
    unsigned short* ar  = Ab  + ((size_t)bh * NP256 + n) * NP224;
    unsigned short* ar2 = A2b + ((size_t)bh * NP256 + n) * NP224;
#pragma unroll
    for (int j = 0; j < 4; j++) {
        int m = lane + j * 64;
        if (m < NP224) {
            float p = e[j] * inv;
            ar[m]  = f2b(p);
            ar2[m] = f2b(p * p);
        }
    }
}

// =============== ctx GEMM: [attn @ V | attn^2 @ CV] via MFMA ===============
__global__ __launch_bounds__(256) void ctx_gemm(
    const unsigned short* __restrict__ Ab, const unsigned short* __restrict__ A2b,
    const unsigned short* __restrict__ vT, const unsigned short* __restrict__ cvT,
    unsigned short* __restrict__ ctxm, unsigned short* __restrict__ ctxc)
{
    __shared__ unsigned short lA1[128 * 32];
    __shared__ unsigned short lA2[128 * 32];
    __shared__ unsigned short lB[128 * 32];
    const int tid = threadIdx.x, lane = tid & 63, wave = tid >> 6;
    const int wm = wave >> 1, wn = wave & 1;
    const int bh = blockIdx.y;
    const int b = bh / HH, h = bh % HH;
    const int m0 = blockIdx.x * 128;
    const int srow = lane >> 2, skoff = (lane & 3) * 8;
    const int fr = lane & 15, fk = (lane >> 4) * 8;

    f32x4 acc[4][4];
#pragma unroll
    for (int i = 0; i < 4; i++)
#pragma unroll
        for (int j = 0; j < 4; j++) acc[i][j] = (f32x4){0.f, 0.f, 0.f, 0.f};

    for (int k0 = 0; k0 < NP224; k0 += 32) {
#pragma unroll
        for (int i = 0; i < 2; i++) {
            int chunk = wave * 2 + i;
            int row = chunk * 16 + srow;
            size_t aoff = ((size_t)bh * NP256 + m0 + row) * NP224 + k0 + skoff;
            GLD(Ab + aoff,  lA1 + chunk * 512);
            GLD(A2b + aoff, lA2 + chunk * 512);
            const unsigned short* bsrc = (chunk < 4)
                ? (vT  + ((size_t)bh * 64 + row) * NP224)
                : (cvT + ((size_t)bh * 64 + row - 64) * NP224);
            GLD(bsrc + k0 + skoff, lB + chunk * 512);
        }
        __syncthreads();
        const unsigned short* asrc = wn ? lA2 : lA1;
        bf16x8 a[4], bfr[4];
#pragma unroll
        for (int t = 0; t < 4; t++) {
            a[t]   = *(const bf16x8*)(asrc + (wm * 64 + t * 16 + fr) * 32 + fk);
            bfr[t] = *(const bf16x8*)(lB   + (wn * 64 + t * 16 + fr) * 32 + fk);
        }
#pragma unroll
        for (int i = 0; i < 4; i++)
#pragma unroll
            for (int j = 0; j < 4; j++)
                acc[i][j] = __builtin_amdgcn_mfma_f32_16x16x32_bf16(a[i], bfr[j], acc[i][j], 0, 0, 0);
        __syncthreads();
    }

    const int lr = (lane >> 4) * 4;
    const int lc = lane & 15;
    unsigned short* dst = wn ? ctxc : ctxm;
#pragma unroll
    for (int i = 0; i < 4; i++) {
#pragma unroll
        for (int j = 0; j < 4; j++) {
            int dcol = j * 16 + lc;   // 0..63
#pragma unroll
            for (int r = 0; r < 4; r++) {
                int n = m0 + wm * 64 + i * 16 + lr + r;
                if (n >= NN) continue;
                dst[((size_t)(b * NN + n)) * EE + h * DD + dcol] = f2b(acc[i][j][r]);
            }
        }
    }
}

// =============== fp32 GEMM (head only) ===============
__global__ __launch_bounds__(256) void gemm_kernel(
    const float* __restrict__ A, const float* __restrict__ W,
    const float* __restrict__ bias, float* __restrict__ C,
    int M, int Nc, int K)
{
    __shared__ float As[16][64];
    __shared__ float Bs[16][64];
    const int tid = threadIdx.x;
    const int tm = tid >> 4;
    const int tn = tid & 15;
    const int m0 = blockIdx.y * 64;
    const int n0 = blockIdx.x * 64;
    float acc[4][4] = {};
    for (int k0 = 0; k0 < K; k0 += 16) {
#pragma unroll
        for (int i = 0; i < 4; i++) {
            int idx = tid + i * 256;
            int r = idx >> 4;
            int c = idx & 15;
            int gm = m0 + r;
            As[c][r] = (gm < M) ? A[(size_t)gm * K + k0 + c] : 0.f;
            int gn = n0 + r;
            Bs[c][r] = (gn < Nc) ? W[(size_t)gn * K + k0 + c] : 0.f;
        }
        __syncthreads();
#pragma unroll
        for (int kk = 0; kk < 16; kk++) {
            float a[4], b[4];
#pragma unroll
            for (int i = 0; i < 4; i++) a[i] = As[kk][tm * 4 + i];
#pragma unroll
            for (int j = 0; j < 4; j++) b[j] = Bs[kk][tn * 4 + j];
#pragma unroll
            for (int i = 0; i < 4; i++)
#pragma unroll
                for (int j = 0; j < 4; j++)
                    acc[i][j] += a[i] * b[j];
        }
        __syncthreads();
    }
#pragma unroll
    for (int i = 0; i < 4; i++) {
        int gm = m0 + tm * 4 + i;
        if (gm >= M) continue;
#pragma unroll
        for (int j = 0; j < 4; j++) {
            int gn = n0 + tn * 4 + j;
            if (gn >= Nc) continue;
            C[(size_t)gm * Nc + gn] = acc[i][j] + (bias ? bias[gn] : 0.f);
        }
    }
}

// =============== fp32 -> bf16 conversion ===============
__global__ __launch_bounds__(256) void cvt_kernel(
    const float* __restrict__ src, unsigned short* __restrict__ dst, int n)
{
    int i = (blockIdx.x * 256 + threadIdx.x) * 4;
    if (i >= n) return;
    float4 f = *(const float4*)(src + i);
    ushort4 u;
    u.x = f2b(f.x); u.y = f2b(f.y); u.z = f2b(f.z); u.w = f2b(f.w);
    *(ushort4*)(dst + i) = u;
}

#define W_QKV   0
#define W_PROJ  1769472
#define W_CPROJ 2359296
#define W_FC1   2949120
#define W_FC2   5308416
#define W_TOTAL 7667712

__global__ __launch_bounds__(256) void cvt_layer_kernel(
    const float* __restrict__ qkvw, const float* __restrict__ pw,
    const float* __restrict__ cpw, const float* __restrict__ f1,
    const float* __restrict__ f2, unsigned short* __restrict__ dst)
{
    int i = (blockIdx.x * 256 + threadIdx.x) * 4;
    if (i >= W_TOTAL) return;
    const float* s; int off;
    if (i < W_PROJ)        { s = qkvw; off = W_QKV; }
    else if (i < W_CPROJ)  { s = pw;   off = W_PROJ; }
    else if (i < W_FC1)    { s = cpw;  off = W_CPROJ; }
    else if (i < W_FC2)    { s = f1;   off = W_FC1; }
    else                   { s = f2;   off = W_FC2; }
    float4 f = *(const float4*)(s + (i - off));
    ushort4 u;
    u.x = f2b(f.x); u.y = f2b(f.y); u.z = f2b(f.z); u.w = f2b(f.w);
    *(ushort4*)(dst + i) = u;
}

// =============== im2col (bf16 out) ===============
__global__ __launch_bounds__(256) void im2col_kernel(
    const float* __restrict__ x, unsigned short* __restrict__ col)
{
    int idx = blockIdx.x * 256 + threadIdx.x;
    if (idx >= PROWS * EE) return;
    int c = idx % EE;
    int r = idx / EE;
    int b = r / NPATCH;
    int p = r % NPATCH;
    int ph = p / 14, pw = p % 14;
    int ch = c >> 8;
    int rem = c & 255;
    int i = rem >> 4, j = rem & 15;
    col[idx] = f2b(x[(((size_t)b * 3 + ch) * 224 + (ph * 16 + i)) * 224 + (pw * 16 + j)]);
}

// =============== assemble tokens ===============
__global__ __launch_bounds__(256) void assemble_kernel(
    const float* __restrict__ tm, const float* __restrict__ tc,
    const float* __restrict__ cls, const float* __restrict__ ccls,
    float* __restrict__ xm, float* __restrict__ xc)
{
    int idx = blockIdx.x * 256 + threadIdx.x;
    if (idx >= NROWS * EE) return;
    int e = idx % EE;
    int r = idx / EE;
    int b = r / NN, n = r % NN;
    if (n == 0) {
        xm[idx] = cls[e];
        xc[idx] = ccls[e];
    } else {
        size_t s = ((size_t)(b * NPATCH + n - 1)) * EE + e;
        xm[idx] = tm[s];
        xc[idx] = tc[s];
    }
}

// =============== LayerNorm (fp32 in, bf16 out) ===============
__global__ __launch_bounds__(256) void ln_kernel(
    const float* __restrict__ x, unsigned short* __restrict__ y,
    const float* __restrict__ g, const float* __restrict__ bb)
{
    int row = blockIdx.x;
    int tid = threadIdx.x;
    __shared__ float red[256];
    const float* xr = x + (size_t)row * EE;
    float v0 = xr[tid], v1 = xr[tid + 256], v2 = xr[tid + 512];
    red[tid] = v0 + v1 + v2;
    __syncthreads();
    for (int s = 128; s > 0; s >>= 1) { if (tid < s) red[tid] += red[tid + s]; __syncthreads(); }
    float mu = red[0] * (1.f / 768.f);
    __syncthreads();
    float d0 = v0 - mu, d1 = v1 - mu, d2 = v2 - mu;
    red[tid] = d0 * d0 + d1 * d1 + d2 * d2;
    __syncthreads();
    for (int s = 128; s > 0; s >>= 1) { if (tid < s) red[tid] += red[tid + s]; __syncthreads(); }
    float rstd = rsqrtf(red[0] * (1.f / 768.f) + 1e-5f);
    unsigned short* yr = y + (size_t)row * EE;
    yr[tid]       = f2b(d0 * rstd * g[tid]       + bb[tid]);
    yr[tid + 256] = f2b(d1 * rstd * g[tid + 256] + bb[tid + 256]);
    yr[tid + 512] = f2b(d2 * rstd * g[tid + 512] + bb[tid + 512]);
}

// =============== concat qkv biases ===============
__global__ __launch_bounds__(256) void qkvbias_kernel(
    const float* __restrict__ qb, const float* __restrict__ vb,
    const float* __restrict__ cqb, const float* __restrict__ cvb,
    float* __restrict__ bm, float* __restrict__ bc)
{
    int j = blockIdx.x * 256 + threadIdx.x;
    if (j >= 3 * EE) return;
    float m, c;
    if (j < EE)        { m = qb[j];        c = cqb[j]; }
    else if (j < 2*EE) { m = 0.f;          c = 0.f; }
    else               { m = vb[j - 2*EE]; c = cvb[j - 2*EE]; }
    bm[j] = m;
    bc[j] = c;
}

// =============== mean-pool + LN (fp32) ===============
__global__ __launch_bounds__(256) void pool_ln_kernel(
    const float* __restrict__ xm, float* __restrict__ out,
    const float* __restrict__ g, const float* __restrict__ bb)
{
    int b = blockIdx.x;
    int tid = threadIdx.x;
    __shared__ float red[256];
    float p[3];
#pragma unroll
    for (int i = 0; i < 3; i++) {
        int e = tid + i * 256;
        float s = 0.f;
        for (int n = 1; n < NN; n++) s += xm[((size_t)(b * NN + n)) * EE + e];
        p[i] = s * (1.f / 196.f);
    }
    red[tid] = p[0] + p[1] + p[2];
    __syncthreads();
    for (int s = 128; s > 0; s >>= 1) { if (tid < s) red[tid] += red[tid + s]; __syncthreads(); }
    float mu = red[0] * (1.f / 768.f);
    __syncthreads();
    float d0 = p[0] - mu, d1 = p[1] - mu, d2 = p[2] - mu;
    red[tid] = d0 * d0 + d1 * d1 + d2 * d2;
    __syncthreads();
    for (int s = 128; s > 0; s >>= 1) { if (tid < s) red[tid] += red[tid + s]; __syncthreads(); }
    float rstd = rsqrtf(red[0] * (1.f / 768.f) + 1e-5f);
    out[(size_t)b * EE + tid]       = d0 * rstd * g[tid]       + bb[tid];
    out[(size_t)b * EE + tid + 256] = d1 * rstd * g[tid + 256] + bb[tid + 256];
    out[(size_t)b * EE + tid + 512] = d2 * rstd * g[tid + 512] + bb[tid + 512];
}

// =========================================================================
extern "C" void kernel_launch(void* const* d_in, const int* in_sizes, int n_in,
                              void* d_out, int out_size, void* d_ws, size_t ws_size,
                              hipStream_t stream)
{
    const float* x        = (const float*)d_in[0];
    const float* rpb      = (const float*)d_in[1];
    const float* patch_w  = (const float*)d_in[2];
    const float* patch_b  = (const float*)d_in[3];
    const float* cpatch_w = (const float*)d_in[4];
    const float* cpatch_b = (const float*)d_in[5];
    const float* cls_tok  = (const float*)d_in[6];
    const float* ccls_tok = (const float*)d_in[7];
    const float* norm1_g  = (const float*)d_in[8];
    const float* norm1_b  = (const float*)d_in[9];
    const float* qkv_w    = (const float*)d_in[10];
    const float* q_bias   = (const float*)d_in[11];
    const float* v_bias   = (const float*)d_in[12];
    const float* cq_bias  = (const float*)d_in[13];
    const float* cv_bias  = (const float*)d_in[14];
    const float* proj_w   = (const float*)d_in[15];
    const float* proj_b   = (const float*)d_in[16];
    const float* cproj_w  = (const float*)d_in[17];
    const float* cproj_b  = (const float*)d_in[18];
    const float* gamma1   = (const float*)d_in[19];
    const float* gamma2   = (const float*)d_in[20];
    const float* norm2_g  = (const float*)d_in[21];
    const float* norm2_b  = (const float*)d_in[22];
    const float* fc1_w    = (const float*)d_in[23];
    const float* fc1_b    = (const float*)d_in[24];
    const float* fc2_w    = (const float*)d_in[25];
    const float* fc2_b    = (const float*)d_in[26];
    const float* fcn_g    = (const float*)d_in[27];
    const float* fcn_b    = (const float*)d_in[28];
    const float* head_w   = (const float*)d_in[29];
    const float* head_b   = (const float*)d_in[30];
    float* out = (float*)d_out;

    // ---- workspace layout ----
    char* base = (char*)d_ws;
    size_t off = 0;
    auto alloc = [&](size_t bytes) {
        void* p = base + off;
        off = (off + bytes + 255) & ~(size_t)255;
        return p;
    };
    unsigned short* wbuf  = (unsigned short*)alloc((size_t)W_TOTAL * 2);
    unsigned short* pw_m  = (unsigned short*)alloc((size_t)589824 * 2);
    unsigned short* pw_c  = (unsigned short*)alloc((size_t)589824 * 2);
    float* xm   = (float*)alloc((size_t)MPAD * EE * 4);
    float* xc   = (float*)alloc((size_t)MPAD * EE * 4);
    unsigned short* xn = (unsigned short*)alloc((size_t)MPAD * EE * 2);
    float* qkv  = (float*)alloc((size_t)MPAD * 3 * EE * 4);
    float* cqkv = (float*)alloc((size_t)MPAD * 3 * EE * 4);
    // union region: S (25.2 MB) and hbuf (10.2 MB) have disjoint lifetimes
    char*  un   = (char*)alloc((size_t)NBH * NP256 * NP256 * 4);
    float* S    = (float*)un;
    unsigned short* hbuf = (unsigned short*)un;
    unsigned short* Aq  = (unsigned short*)alloc((size_t)NBH * NP256 * 128 * 2);
    unsigned short* Bk  = (unsigned short*)alloc((size_t)NBH * NP256 * 128 * 2);
    unsigned short* vT  = (unsigned short*)alloc((size_t)NBH * 64 * NP224 * 2);
    unsigned short* cvT = (unsigned short*)alloc((size_t)NBH * 64 * NP224 * 2);
    float* rsum = (float*)alloc((size_t)NBH * NP256 * 4);
    float* csum = (float*)alloc((size_t)NBH * NP256 * 4);
    unsigned short* ctxm = (unsigned short*)alloc((size_t)MPAD * EE * 2);
    unsigned short* ctxc = (unsigned short*)alloc((size_t)MPAD * EE * 2);
    unsigned short* colb = (unsigned short*)alloc((size_t)MPAD * EE * 2);
    float* biasq  = (float*)alloc(3 * EE * 4);
    float* biasc  = (float*)alloc(3 * EE * 4);
    float* pooled = (float*)alloc((size_t)BB * EE * 4);
    // attn bf16 buffers alias qkv/cqkv (dead after pre_kernel each layer)
    unsigned short* Ab  = (unsigned short*)qkv;
    unsigned short* A2b = (unsigned short*)cqkv;
    // patch-embed fp32 outputs alias qkv buffers
    float* tm = qkv;
    float* tc = cqkv;

    dim3 t256(256);

    // ---- patch embed ----
    cvt_kernel<<<dim3(589824 / 4 / 256), t256, 0, stream>>>(patch_w, pw_m, 589824);
    cvt_kernel<<<dim3(589824 / 4 / 256), t256, 0, stream>>>(cpatch_w, pw_c, 589824);
    im2col_kernel<<<dim3((PROWS * EE + 255) / 256), t256, 0, stream>>>(x, colb);
    {
        dim3 grid(EE / 128, MPAD / 128);
        mfma_gemm<<<grid, t256, 0, stream>>>(colb, pw_m, patch_b, EE, EE, MODE_F32,
                                             nullptr, nullptr, tm, nullptr);
        mfma_gemm<<<grid, t256, 0, stream>>>(colb, pw_c, cpatch_b, EE, EE, MODE_F32,
                                             nullptr, nullptr, tc, nullptr);
    }
    assemble_kernel<<<dim3((NROWS * EE + 255) / 256), t256, 0, stream>>>(
        tm, tc, cls_tok, ccls_tok, xm, xc);

    dim3 gridQKV(3 * EE / 128, MPAD / 128);
    dim3 gridE(EE / 128, MPAD / 128);
    dim3 gridMLP(MLPD / 128, MPAD / 128);
    dim3 gridPre(NP256, NBH);
    dim3 gridWass(2, 2, NBH);
    dim3 gridSm((NBH * NN + 3) / 4);
    dim3 gridCtx(2, NBH);
    dim3 gridCvtL((W_TOTAL / 4 + 255) / 256);

    for (int l = 0; l < LL; l++) {
        cvt_layer_kernel<<<gridCvtL, t256, 0, stream>>>(
            qkv_w + (size_t)l * 3 * EE * EE, proj_w + (size_t)l * EE * EE,
            cproj_w + (size_t)l * EE * EE, fc1_w + (size_t)l * MLPD * EE,
            fc2_w + (size_t)l * EE * MLPD, wbuf);
        qkvbias_kernel<<<dim3(9), t256, 0, stream>>>(
            q_bias + l * EE, v_bias + l * EE, cq_bias + l * EE, cv_bias + l * EE,
            biasq, biasc);

        ln_kernel<<<dim3(NROWS), t256, 0, stream>>>(xm, xn, norm1_g + l * EE, norm1_b + l * EE);
        mfma_gemm<<<gridQKV, t256, 0, stream>>>(xn, wbuf + W_QKV, biasq, EE, 3 * EE,
                                                MODE_F32, nullptr, nullptr, qkv, nullptr);
        ln_kernel<<<dim3(NROWS), t256, 0, stream>>>(xc, xn, norm1_g + l * EE, norm1_b + l * EE);
        mfma_gemm<<<gridQKV, t256, 0, stream>>>(xn, wbuf + W_QKV, biasc, EE, 3 * EE,
                                                MODE_ELU1F, nullptr, nullptr, cqkv, nullptr);

        // attention (MFMA path)
        pre_kernel<<<gridPre, dim3(64), 0, stream>>>(qkv, cqkv, Aq, Bk, rsum, csum, vT, cvT);
        wass_gemm<<<gridWass, t256, 0, stream>>>(Aq, Bk, rsum, csum, rpb, S);
        softmax_kernel<<<gridSm, t256, 0, stream>>>(S, Ab, A2b);
        ctx_gemm<<<gridCtx, t256, 0, stream>>>(Ab, A2b, vT, cvT, ctxm, ctxc);

        // proj + residual
        mfma_gemm<<<gridE, t256, 0, stream>>>(ctxm, wbuf + W_PROJ, proj_b + l * EE, EE, EE,
                                              MODE_RESF, gamma1 + l * EE, xm, xm, nullptr);
        mfma_gemm<<<gridE, t256, 0, stream>>>(ctxc, wbuf + W_CPROJ, cproj_b + l * EE, EE, EE,
                                              MODE_RESF, gamma1 + l * EE, xc, xc, nullptr);

        // MLP (mean)
        ln_kernel<<<dim3(NROWS), t256, 0, stream>>>(xm, xn, norm2_g + l * EE, norm2_b + l * EE);
        mfma_gemm<<<gridMLP, t256, 0, stream>>>(xn, wbuf + W_FC1, fc1_b + l * MLPD, EE, MLPD,
                                                MODE_GELUB, nullptr, nullptr, nullptr, hbuf);
        mfma_gemm<<<gridE, t256, 0, stream>>>(hbuf, wbuf + W_FC2, fc2_b + l * EE, MLPD, EE,
                                              MODE_RESF, gamma2 + l * EE, xm, xm, nullptr);

        // MLP (cov)
        ln_kernel<<<dim3(NROWS), t256, 0, stream>>>(xc, xn, norm2_g + l * EE, norm2_b + l * EE);
        mfma_gemm<<<gridMLP, t256, 0, stream>>>(xn, wbuf + W_FC1, fc1_b + l * MLPD, EE, MLPD,
                                                MODE_GELUB, nullptr, nullptr, nullptr, hbuf);
        mfma_gemm<<<gridE, t256, 0, stream>>>(hbuf, wbuf + W_FC2, fc2_b + l * EE, MLPD, EE,
                                              MODE_RESF, gamma2 + l * EE, xc, xc, nullptr);
    }

    // ---- head ----
    pool_ln_kernel<<<dim3(BB), t256, 0, stream>>>(xm, pooled, fcn_g, fcn_b);
    {
        dim3 grid((NCLS + 63) / 64, (BB + 63) / 64);
        gemm_kernel<<<grid, t256, 0, stream>>>(pooled, head_w, head_b, out, BB, NCLS, EE);
    }
}

// Round 4
// 3977.898 us; speedup vs baseline: 6.6398x; 1.7143x over previous
//
#include <hip/hip_runtime.h>
#include <hip/hip_bf16.h>
#include <math.h>

#define BB 8
#define EE 768
#define HH 12
#define LL 12
#define DD 64
#define MLPD 3072
#define NN 197
#define NPATCH 196
#define NCLS 1000
#define NROWS (BB*NN)        // 1576
#define PROWS (BB*NPATCH)    // 1568
#define MPAD 1664            // 13 * 128
#define HTILES 13            // MPAD/128
#define NBH (BB*HH)          // 96
#define NP224 224
#define NP256 256
#define SCALE 0.125f

#define MODE_F32   0
#define MODE_ELU1F 1
#define MODE_GELUB 2
#define MODE_RESF  3

typedef __attribute__((ext_vector_type(8))) short bf16x8;
typedef __attribute__((ext_vector_type(4))) float f32x4;

__device__ __forceinline__ unsigned short f2b(float f) {
    union { __hip_bfloat16 h; unsigned short u; } x;
    x.h = __float2bfloat16(f);
    return x.u;
}

#define GLD(gptr, lptr) __builtin_amdgcn_global_load_lds( \
    (const __attribute__((address_space(1))) unsigned int*)(gptr), \
    (__attribute__((address_space(3))) unsigned int*)(lptr), 16, 0, 0)

// =============== dual-half MFMA bf16 GEMM ===============
// blockIdx.y in [0,26): half = y>=13 selects {A,W,bias,mode,resid,out} set.
// A row index = mout0+row into the selected A pointer (pass A1=A0+MPAD*K for
// stacked activations, A1=A0 for shared A).
__global__ __launch_bounds__(256) void mfma_gemm2(
    const unsigned short* __restrict__ A0, const unsigned short* __restrict__ A1,
    const unsigned short* __restrict__ W0, const unsigned short* __restrict__ W1,
    const float* __restrict__ bias0, const float* __restrict__ bias1,
    int K, int Nc, int mode0, int mode1,
    const float* __restrict__ gamma,
    const float* __restrict__ resid0, const float* __restrict__ resid1,
    float* __restrict__ Cf0, float* __restrict__ Cf1,
    unsigned short* __restrict__ Cb0, unsigned short* __restrict__ Cb1)
{
    __shared__ unsigned short lA[128 * 32];
    __shared__ unsigned short lB[128 * 32];
    const int tid  = threadIdx.x;
    const int lane = tid & 63;
    const int wave = tid >> 6;
    const int wm = wave >> 1, wn = wave & 1;
    const int half = blockIdx.y >= HTILES;
    const int mout0 = (blockIdx.y - (half ? HTILES : 0)) * 128;
    const int n0 = blockIdx.x * 128;
    const unsigned short* A = half ? A1 : A0;
    const unsigned short* W = half ? W1 : W0;
    const float* bias = half ? bias1 : bias0;
    const float* resid = half ? resid1 : resid0;
    float* Cf = half ? Cf1 : Cf0;
    unsigned short* Cb = half ? Cb1 : Cb0;
    const int mode = half ? mode1 : mode0;

    const int srow  = lane >> 2;
    const int skoff = (lane & 3) * 8;
    const int fr = lane & 15;
    const int fk = (lane >> 4) * 8;

    f32x4 acc[4][4];
#pragma unroll
    for (int i = 0; i < 4; i++)
#pragma unroll
        for (int j = 0; j < 4; j++) acc[i][j] = (f32x4){0.f, 0.f, 0.f, 0.f};

    for (int k0 = 0; k0 < K; k0 += 32) {
#pragma unroll
        for (int i = 0; i < 2; i++) {
            int chunk = wave * 2 + i;
            int row = chunk * 16 + srow;
            GLD(A + (size_t)(mout0 + row) * K + k0 + skoff, lA + chunk * 512);
            GLD(W + (size_t)(n0 + row) * K + k0 + skoff, lB + chunk * 512);
        }
        __syncthreads();
        bf16x8 a[4], b[4];
#pragma unroll
        for (int t = 0; t < 4; t++) {
            a[t] = *(const bf16x8*)(lA + (wm * 64 + t * 16 + fr) * 32 + fk);
            b[t] = *(const bf16x8*)(lB + (wn * 64 + t * 16 + fr) * 32 + fk);
        }
#pragma unroll
        for (int i = 0; i < 4; i++)
#pragma unroll
            for (int j = 0; j < 4; j++)
                acc[i][j] = __builtin_amdgcn_mfma_f32_16x16x32_bf16(a[i], b[j], acc[i][j], 0, 0, 0);
        __syncthreads();
    }

    const int crow0 = mout0 + wm * 64;
    const int ccol0 = n0 + wn * 64;
    const int lr = (lane >> 4) * 4;
    const int lc = lane & 15;
#pragma unroll
    for (int i = 0; i < 4; i++) {
#pragma unroll
        for (int j = 0; j < 4; j++) {
            int col = ccol0 + j * 16 + lc;
            float bv = bias ? bias[col] : 0.f;
#pragma unroll
            for (int r = 0; r < 4; r++) {
                int row = crow0 + i * 16 + lr + r;
                float v = acc[i][j][r] + bv;
                size_t o = (size_t)row * Nc + col;
                if (mode == MODE_ELU1F) {
                    Cf[o] = (v > 0.f) ? (v + 1.f) : expf(v);
                } else if (mode == MODE_GELUB) {
                    v = 0.5f * v * (1.f + erff(v * 0.70710678118654752f));
                    Cb[o] = f2b(v);
                } else if (mode == MODE_RESF) {
                    Cf[o] = resid[o] + gamma[col] * v;
                } else {
                    Cf[o] = v;
                }
            }
        }
    }
}

// =============== attention pre: operands + coalesced transpose ===============
// grid (4, NBH), 256 threads. Tile t covers 64 token slots.
__global__ __launch_bounds__(256) void pre_kernel(
    const float* __restrict__ qkv, const float* __restrict__ cqkv,
    unsigned short* __restrict__ Aq, unsigned short* __restrict__ Bk,
    float* __restrict__ rsum, float* __restrict__ csum,
    unsigned short* __restrict__ vT, unsigned short* __restrict__ cvT)
{
    const int t = blockIdx.x;
    const int bh = blockIdx.y;
    const int b = bh / HH, h = bh % HH;
    const int n0 = t * 64;
    const int lane = threadIdx.x & 63;
    const int w = threadIdx.x >> 6;
    __shared__ unsigned short vs[64][66];
    __shared__ unsigned short cvs[64][66];

    for (int p = 0; p < 16; p++) {
        int nl = p * 4 + w;
        int n = n0 + nl;
        int d = lane;
        size_t arow = ((size_t)bh * NP256 + n) * 128;
        if (n < NN) {
            size_t basei = (size_t)(b * NN + n) * 3 * EE + h * DD + d;
            float q  = qkv[basei];
            float k  = qkv[basei + EE];
            float v  = qkv[basei + 2 * EE];
            float cq = cqkv[basei];
            float ck = cqkv[basei + EE];
            float cv = cqkv[basei + 2 * EE];
            float qs = q * SCALE;
            float sqq = sqrtf(fmaxf(cq, 1e-24f));
            float sqk = sqrtf(fmaxf(ck, 1e-24f));
            Aq[arow + d]      = f2b(qs);
            Aq[arow + 64 + d] = f2b(sqq);
            Bk[arow + d]      = f2b(k);
            Bk[arow + 64 + d] = f2b(sqk);
            vs[nl][d]  = f2b(v);
            cvs[nl][d] = f2b(cv);
            float r = qs * qs + cq;
            float c = k * k + ck;
            for (int off2 = 32; off2 > 0; off2 >>= 1) {
                r += __shfl_down(r, off2);
                c += __shfl_down(c, off2);
            }
            if (d == 0) { rsum[bh * NP256 + n] = r; csum[bh * NP256 + n] = c; }
        } else {
            ((unsigned int*)(Aq + arow))[d] = 0u;
            ((unsigned int*)(Bk + arow))[d] = 0u;
            vs[nl][d] = 0; cvs[nl][d] = 0;
            if (d == 0) { rsum[bh * NP256 + n] = 0.f; csum[bh * NP256 + n] = 0.f; }
        }
    }
    __syncthreads();
    for (int p = 0; p < 16; p++) {
        int dr = p * 4 + w;
        int n = n0 + lane;
        if (n < NP224) {
            vT [((size_t)bh * 64 + dr) * NP224 + n] = vs[lane][dr];
            cvT[((size_t)bh * 64 + dr) * NP224 + n] = cvs[lane][dr];
        }
    }
}

// =============== Wasserstein logits via MFMA + fused sigmoid + rpb ===============
__global__ __launch_bounds__(256) void wass_gemm(
    const unsigned short* __restrict__ Aq, const unsigned short* __restrict__ Bk,
    const float* __restrict__ rsum, const float* __restrict__ csum,
    const float* __restrict__ rpb, float* __restrict__ S)
{
    __shared__ unsigned short lA[128 * 32];
    __shared__ unsigned short lB[128 * 32];
    const int tid = threadIdx.x, lane = tid & 63, wave = tid >> 6;
    const int wm = wave >> 1, wn = wave & 1;
    const int bh = blockIdx.z;
    const int h = bh % HH;
    const int m0 = blockIdx.y * 128;
    const int n0 = blockIdx.x * 128;
    const unsigned short* A = Aq + (size_t)bh * NP256 * 128;
    const unsigned short* B = Bk + (size_t)bh * NP256 * 128;
    const int srow = lane >> 2, skoff = (lane & 3) * 8;
    const int fr = lane & 15, fk = (lane >> 4) * 8;

    f32x4 acc[4][4];
#pragma unroll
    for (int i = 0; i < 4; i++)
#pragma unroll
        for (int j = 0; j < 4; j++) acc[i][j] = (f32x4){0.f, 0.f, 0.f, 0.f};

    for (int k0 = 0; k0 < 128; k0 += 32) {
#pragma unroll
        for (int i = 0; i < 2; i++) {
            int chunk = wave * 2 + i;
            int row = chunk * 16 + srow;
            GLD(A + (size_t)(m0 + row) * 128 + k0 + skoff, lA + chunk * 512);
            GLD(B + (size_t)(n0 + row) * 128 + k0 + skoff, lB + chunk * 512);
        }
        __syncthreads();
        bf16x8 a[4], b[4];
#pragma unroll
        for (int t = 0; t < 4; t++) {
            a[t] = *(const bf16x8*)(lA + (wm * 64 + t * 16 + fr) * 32 + fk);
            b[t] = *(const bf16x8*)(lB + (wn * 64 + t * 16 + fr) * 32 + fk);
        }
#pragma unroll
        for (int i = 0; i < 4; i++)
#pragma unroll
            for (int j = 0; j < 4; j++)
                acc[i][j] = __builtin_amdgcn_mfma_f32_16x16x32_bf16(a[i], b[j], acc[i][j], 0, 0, 0);
        __syncthreads();
    }

    const int lr = (lane >> 4) * 4;
    const int lc = lane & 15;
#pragma unroll
    for (int i = 0; i < 4; i++) {
#pragma unroll
        for (int j = 0; j < 4; j++) {
            int m = n0 + wn * 64 + j * 16 + lc;
            float cs = csum[bh * NP256 + m];
#pragma unroll
            for (int r = 0; r < 4; r++) {
                int n = m0 + wm * 64 + i * 16 + lr + r;
                float z = 2.f * acc[i][j][r] - rsum[bh * NP256 + n] - cs + 1e-24f;
                float s = 1.f / (1.f + expf(-z));
                float rp = (n < NN && m < NN) ? rpb[((size_t)h * NN + n) * NN + m] : 0.f;
                S[((size_t)bh * NP256 + n) * NP256 + m] = s + rp;
            }
        }
    }
}

// =============== softmax over m; emit bf16 attn and attn^2 ===============
__global__ __launch_bounds__(256) void softmax_kernel(
    const float* __restrict__ S, unsigned short* __restrict__ Ab,
    unsigned short* __restrict__ A2b)
{
    const int wave = threadIdx.x >> 6, lane = threadIdx.x & 63;
    const int idx = blockIdx.x * 4 + wave;
    if (idx >= NBH * NN) return;
    const int bh = idx / NN, n = idx % NN;
    const float* row = S + ((size_t)bh * NP256 + n) * NP256;
    float l[4], mx = -1e30f;
#pragma unroll
    for (int j = 0; j < 4; j++) {
        int m = lane + j * 64;
        l[j] = (m < NN) ? row[m] : -1e30f;
        mx = fmaxf(mx, l[j]);
    }
    for (int off = 32; off > 0; off >>= 1) mx = fmaxf(mx, __shfl_xor(mx, off));
    float e[4], sum = 0.f;
#pragma unroll
    for (int j = 0; j < 4; j++) {
        int m = lane + j * 64;
        e[j] = (m < NN) ? expf(l[j] - mx) : 0.f;
        sum += e[j];
    }
    for (int off = 32; off > 0; off >>= 1) sum += __shfl_xor(sum, off);
    float inv = 1.f / sum;
    unsigned short* ar  = Ab  + ((size_t)bh * NP256 + n) * NP224;
    unsigned short* ar2 = A2b + ((size_t)bh * NP256 + n) * NP224;
#pragma unroll
    for (int j = 0; j < 4; j++) {
        int m = lane + j * 64;
        if (m < NP224) {
            float p = e[j] * inv;
            ar[m]  = f2b(p);
            ar2[m] = f2b(p * p);
        }
    }
}

// =============== ctx GEMM: [attn @ V | attn^2 @ CV] via MFMA ===============
__global__ __launch_bounds__(256) void ctx_gemm(
    const unsigned short* __restrict__ Ab, const unsigned short* __restrict__ A2b,
    const unsigned short* __restrict__ vT, const unsigned short* __restrict__ cvT,
    unsigned short* __restrict__ ctxm, unsigned short* __restrict__ ctxc)
{
    __shared__ unsigned short lA1[128 * 32];
    __shared__ unsigned short lA2[128 * 32];
    __shared__ unsigned short lB[128 * 32];
    const int tid = threadIdx.x, lane = tid & 63, wave = tid >> 6;
    const int wm = wave >> 1, wn = wave & 1;
    const int bh = blockIdx.y;
    const int b = bh / HH, h = bh % HH;
    const int m0 = blockIdx.x * 128;
    const int srow = lane >> 2, skoff = (lane & 3) * 8;
    const int fr = lane & 15, fk = (lane >> 4) * 8;

    f32x4 acc[4][4];
#pragma unroll
    for (int i = 0; i < 4; i++)
#pragma unroll
        for (int j = 0; j < 4; j++) acc[i][j] = (f32x4){0.f, 0.f, 0.f, 0.f};

    for (int k0 = 0; k0 < NP224; k0 += 32) {
#pragma unroll
        for (int i = 0; i < 2; i++) {
            int chunk = wave * 2 + i;
            int row = chunk * 16 + srow;
            size_t aoff = ((size_t)bh * NP256 + m0 + row) * NP224 + k0 + skoff;
            GLD(Ab + aoff,  lA1 + chunk * 512);
            GLD(A2b + aoff, lA2 + chunk * 512);
            const unsigned short* bsrc = (chunk < 4)
                ? (vT  + ((size_t)bh * 64 + row) * NP224)
                : (cvT + ((size_t)bh * 64 + row - 64) * NP224);
            GLD(bsrc + k0 + skoff, lB + chunk * 512);
        }
        __syncthreads();
        const unsigned short* asrc = wn ? lA2 : lA1;
        bf16x8 a[4], bfr[4];
#pragma unroll
        for (int t = 0; t < 4; t++) {
            a[t]   = *(const bf16x8*)(asrc + (wm * 64 + t * 16 + fr) * 32 + fk);
            bfr[t] = *(const bf16x8*)(lB   + (wn * 64 + t * 16 + fr) * 32 + fk);
        }
#pragma unroll
        for (int i = 0; i < 4; i++)
#pragma unroll
            for (int j = 0; j < 4; j++)
                acc[i][j] = __builtin_amdgcn_mfma_f32_16x16x32_bf16(a[i], bfr[j], acc[i][j], 0, 0, 0);
        __syncthreads();
    }

    const int lr = (lane >> 4) * 4;
    const int lc = lane & 15;
    unsigned short* dst = wn ? ctxc : ctxm;
#pragma unroll
    for (int i = 0; i < 4; i++) {
#pragma unroll
        for (int j = 0; j < 4; j++) {
            int dcol = j * 16 + lc;
#pragma unroll
            for (int r = 0; r < 4; r++) {
                int n = m0 + wm * 64 + i * 16 + lr + r;
                if (n >= NN) continue;
                dst[((size_t)(b * NN + n)) * EE + h * DD + dcol] = f2b(acc[i][j][r]);
            }
        }
    }
}

// =============== fp32 GEMM (head only) ===============
__global__ __launch_bounds__(256) void gemm_kernel(
    const float* __restrict__ A, const float* __restrict__ W,
    const float* __restrict__ bias, float* __restrict__ C,
    int M, int Nc, int K)
{
    __shared__ float As[16][64];
    __shared__ float Bs[16][64];
    const int tid = threadIdx.x;
    const int tm = tid >> 4;
    const int tn = tid & 15;
    const int m0 = blockIdx.y * 64;
    const int n0 = blockIdx.x * 64;
    float acc[4][4] = {};
    for (int k0 = 0; k0 < K; k0 += 16) {
#pragma unroll
        for (int i = 0; i < 4; i++) {
            int idx = tid + i * 256;
            int r = idx >> 4;
            int c = idx & 15;
            int gm = m0 + r;
            As[c][r] = (gm < M) ? A[(size_t)gm * K + k0 + c] : 0.f;
            int gn = n0 + r;
            Bs[c][r] = (gn < Nc) ? W[(size_t)gn * K + k0 + c] : 0.f;
        }
        __syncthreads();
#pragma unroll
        for (int kk = 0; kk < 16; kk++) {
            float a[4], b[4];
#pragma unroll
            for (int i = 0; i < 4; i++) a[i] = As[kk][tm * 4 + i];
#pragma unroll
            for (int j = 0; j < 4; j++) b[j] = Bs[kk][tn * 4 + j];
#pragma unroll
            for (int i = 0; i < 4; i++)
#pragma unroll
                for (int j = 0; j < 4; j++)
                    acc[i][j] += a[i] * b[j];
        }
        __syncthreads();
    }
#pragma unroll
    for (int i = 0; i < 4; i++) {
        int gm = m0 + tm * 4 + i;
        if (gm >= M) continue;
#pragma unroll
        for (int j = 0; j < 4; j++) {
            int gn = n0 + tn * 4 + j;
            if (gn >= Nc) continue;
            C[(size_t)gm * Nc + gn] = acc[i][j] + (bias ? bias[gn] : 0.f);
        }
    }
}

// =============== fp32 -> bf16 conversion ===============
__global__ __launch_bounds__(256) void cvt_kernel(
    const float* __restrict__ src, unsigned short* __restrict__ dst, int n)
{
    int i = (blockIdx.x * 256 + threadIdx.x) * 4;
    if (i >= n) return;
    float4 f = *(const float4*)(src + i);
    ushort4 u;
    u.x = f2b(f.x); u.y = f2b(f.y); u.z = f2b(f.z); u.w = f2b(f.w);
    *(ushort4*)(dst + i) = u;
}

#define W_QKV   0
#define W_PROJ  1769472
#define W_CPROJ 2359296
#define W_FC1   2949120
#define W_FC2   5308416
#define W_TOTAL 7667712

__global__ __launch_bounds__(256) void cvt_layer_kernel(
    const float* __restrict__ qkvw, const float* __restrict__ pw,
    const float* __restrict__ cpw, const float* __restrict__ f1,
    const float* __restrict__ f2, unsigned short* __restrict__ dst)
{
    int i = (blockIdx.x * 256 + threadIdx.x) * 4;
    if (i >= W_TOTAL) return;
    const float* s; int off;
    if (i < W_PROJ)        { s = qkvw; off = W_QKV; }
    else if (i < W_CPROJ)  { s = pw;   off = W_PROJ; }
    else if (i < W_FC1)    { s = cpw;  off = W_CPROJ; }
    else if (i < W_FC2)    { s = f1;   off = W_FC1; }
    else                   { s = f2;   off = W_FC2; }
    float4 f = *(const float4*)(s + (i - off));
    ushort4 u;
    u.x = f2b(f.x); u.y = f2b(f.y); u.z = f2b(f.z); u.w = f2b(f.w);
    *(ushort4*)(dst + i) = u;
}

// =============== im2col (bf16 out) ===============
__global__ __launch_bounds__(256) void im2col_kernel(
    const float* __restrict__ x, unsigned short* __restrict__ col)
{
    int idx = blockIdx.x * 256 + threadIdx.x;
    if (idx >= PROWS * EE) return;
    int c = idx % EE;
    int r = idx / EE;
    int b = r / NPATCH;
    int p = r % NPATCH;
    int ph = p / 14, pw = p % 14;
    int ch = c >> 8;
    int rem = c & 255;
    int i = rem >> 4, j = rem & 15;
    col[idx] = f2b(x[(((size_t)b * 3 + ch) * 224 + (ph * 16 + i)) * 224 + (pw * 16 + j)]);
}

// =============== assemble tokens ===============
__global__ __launch_bounds__(256) void assemble_kernel(
    const float* __restrict__ tm, const float* __restrict__ tc,
    const float* __restrict__ cls, const float* __restrict__ ccls,
    float* __restrict__ xm, float* __restrict__ xc)
{
    int idx = blockIdx.x * 256 + threadIdx.x;
    if (idx >= NROWS * EE) return;
    int e = idx % EE;
    int r = idx / EE;
    int b = r / NN, n = r % NN;
    if (n == 0) {
        xm[idx] = cls[e];
        xc[idx] = ccls[e];
    } else {
        size_t s = ((size_t)(b * NPATCH + n - 1)) * EE + e;
        xm[idx] = tm[s];
        xc[idx] = tc[s];
    }
}

// =============== merged LayerNorm for both streams (fp32 in, bf16 out) ===============
// grid 2*NROWS: rows < NROWS -> xm -> xn2 rows [0,NROWS);
//               rows >= NROWS -> xc -> xn2 rows [MPAD, MPAD+NROWS)
__global__ __launch_bounds__(256) void ln2_kernel(
    const float* __restrict__ xm, const float* __restrict__ xc,
    unsigned short* __restrict__ y, const float* __restrict__ g,
    const float* __restrict__ bb)
{
    int row = blockIdx.x;
    int tid = threadIdx.x;
    const float* src;
    size_t orow;
    if (row < NROWS) { src = xm + (size_t)row * EE; orow = row; }
    else { src = xc + (size_t)(row - NROWS) * EE; orow = (size_t)(row - NROWS) + MPAD; }
    __shared__ float red[256];
    float v0 = src[tid], v1 = src[tid + 256], v2 = src[tid + 512];
    red[tid] = v0 + v1 + v2;
    __syncthreads();
    for (int s = 128; s > 0; s >>= 1) { if (tid < s) red[tid] += red[tid + s]; __syncthreads(); }
    float mu = red[0] * (1.f / 768.f);
    __syncthreads();
    float d0 = v0 - mu, d1 = v1 - mu, d2 = v2 - mu;
    red[tid] = d0 * d0 + d1 * d1 + d2 * d2;
    __syncthreads();
    for (int s = 128; s > 0; s >>= 1) { if (tid < s) red[tid] += red[tid + s]; __syncthreads(); }
    float rstd = rsqrtf(red[0] * (1.f / 768.f) + 1e-5f);
    unsigned short* yr = y + orow * EE;
    yr[tid]       = f2b(d0 * rstd * g[tid]       + bb[tid]);
    yr[tid + 256] = f2b(d1 * rstd * g[tid + 256] + bb[tid + 256]);
    yr[tid + 512] = f2b(d2 * rstd * g[tid + 512] + bb[tid + 512]);
}

// =============== concat qkv biases ===============
__global__ __launch_bounds__(256) void qkvbias_kernel(
    const float* __restrict__ qb, const float* __restrict__ vb,
    const float* __restrict__ cqb, const float* __restrict__ cvb,
    float* __restrict__ bm, float* __restrict__ bc)
{
    int j = blockIdx.x * 256 + threadIdx.x;
    if (j >= 3 * EE) return;
    float m, c;
    if (j < EE)        { m = qb[j];        c = cqb[j]; }
    else if (j < 2*EE) { m = 0.f;          c = 0.f; }
    else               { m = vb[j - 2*EE]; c = cvb[j - 2*EE]; }
    bm[j] = m;
    bc[j] = c;
}

// =============== mean-pool + LN (fp32) ===============
__global__ __launch_bounds__(256) void pool_ln_kernel(
    const float* __restrict__ xm, float* __restrict__ out,
    const float* __restrict__ g, const float* __restrict__ bb)
{
    int b = blockIdx.x;
    int tid = threadIdx.x;
    __shared__ float red[256];
    float p[3];
#pragma unroll
    for (int i = 0; i < 3; i++) {
        int e = tid + i * 256;
        float s = 0.f;
        for (int n = 1; n < NN; n++) s += xm[((size_t)(b * NN + n)) * EE + e];
        p[i] = s * (1.f / 196.f);
    }
    red[tid] = p[0] + p[1] + p[2];
    __syncthreads();
    for (int s = 128; s > 0; s >>= 1) { if (tid < s) red[tid] += red[tid + s]; __syncthreads(); }
    float mu = red[0] * (1.f / 768.f);
    __syncthreads();
    float d0 = p[0] - mu, d1 = p[1] - mu, d2 = p[2] - mu;
    red[tid] = d0 * d0 + d1 * d1 + d2 * d2;
    __syncthreads();
    for (int s = 128; s > 0; s >>= 1) { if (tid < s) red[tid] += red[tid + s]; __syncthreads(); }
    float rstd = rsqrtf(red[0] * (1.f / 768.f) + 1e-5f);
    out[(size_t)b * EE + tid]       = d0 * rstd * g[tid]       + bb[tid];
    out[(size_t)b * EE + tid + 256] = d1 * rstd * g[tid + 256] + bb[tid + 256];
    out[(size_t)b * EE + tid + 512] = d2 * rstd * g[tid + 512] + bb[tid + 512];
}

// =========================================================================
extern "C" void kernel_launch(void* const* d_in, const int* in_sizes, int n_in,
                              void* d_out, int out_size, void* d_ws, size_t ws_size,
                              hipStream_t stream)
{
    const float* x        = (const float*)d_in[0];
    const float* rpb      = (const float*)d_in[1];
    const float* patch_w  = (const float*)d_in[2];
    const float* patch_b  = (const float*)d_in[3];
    const float* cpatch_w = (const float*)d_in[4];
    const float* cpatch_b = (const float*)d_in[5];
    const float* cls_tok  = (const float*)d_in[6];
    const float* ccls_tok = (const float*)d_in[7];
    const float* norm1_g  = (const float*)d_in[8];
    const float* norm1_b  = (const float*)d_in[9];
    const float* qkv_w    = (const float*)d_in[10];
    const float* q_bias   = (const float*)d_in[11];
    const float* v_bias   = (const float*)d_in[12];
    const float* cq_bias  = (const float*)d_in[13];
    const float* cv_bias  = (const float*)d_in[14];
    const float* proj_w   = (const float*)d_in[15];
    const float* proj_b   = (const float*)d_in[16];
    const float* cproj_w  = (const float*)d_in[17];
    const float* cproj_b  = (const float*)d_in[18];
    const float* gamma1   = (const float*)d_in[19];
    const float* gamma2   = (const float*)d_in[20];
    const float* norm2_g  = (const float*)d_in[21];
    const float* norm2_b  = (const float*)d_in[22];
    const float* fc1_w    = (const float*)d_in[23];
    const float* fc1_b    = (const float*)d_in[24];
    const float* fc2_w    = (const float*)d_in[25];
    const float* fc2_b    = (const float*)d_in[26];
    const float* fcn_g    = (const float*)d_in[27];
    const float* fcn_b    = (const float*)d_in[28];
    const float* head_w   = (const float*)d_in[29];
    const float* head_b   = (const float*)d_in[30];
    float* out = (float*)d_out;

    // ---- workspace layout ----
    char* base = (char*)d_ws;
    size_t off = 0;
    auto alloc = [&](size_t bytes) {
        void* p = base + off;
        off = (off + bytes + 255) & ~(size_t)255;
        return p;
    };
    unsigned short* wbuf  = (unsigned short*)alloc((size_t)W_TOTAL * 2);
    unsigned short* pw_m  = (unsigned short*)alloc((size_t)589824 * 2);
    unsigned short* pw_c  = (unsigned short*)alloc((size_t)589824 * 2);
    float* xm   = (float*)alloc((size_t)MPAD * EE * 4);
    float* xc   = (float*)alloc((size_t)MPAD * EE * 4);
    unsigned short* xn2 = (unsigned short*)alloc((size_t)2 * MPAD * EE * 2);
    float* qkv  = (float*)alloc((size_t)MPAD * 3 * EE * 4);
    float* cqkv = (float*)alloc((size_t)MPAD * 3 * EE * 4);
    // union region: S (25.2 MB) and hbuf (20.4 MB) have disjoint lifetimes
    char*  un   = (char*)alloc((size_t)NBH * NP256 * NP256 * 4);
    float* S    = (float*)un;
    unsigned short* hbuf = (unsigned short*)un;   // [2*MPAD][MLPD]
    unsigned short* Aq  = (unsigned short*)alloc((size_t)NBH * NP256 * 128 * 2);
    unsigned short* Bk  = (unsigned short*)alloc((size_t)NBH * NP256 * 128 * 2);
    unsigned short* vT  = (unsigned short*)alloc((size_t)NBH * 64 * NP224 * 2);
    unsigned short* cvT = (unsigned short*)alloc((size_t)NBH * 64 * NP224 * 2);
    float* rsum = (float*)alloc((size_t)NBH * NP256 * 4);
    float* csum = (float*)alloc((size_t)NBH * NP256 * 4);
    unsigned short* ctx2 = (unsigned short*)alloc((size_t)2 * MPAD * EE * 2);
    unsigned short* colb = (unsigned short*)alloc((size_t)MPAD * EE * 2);
    float* biasq  = (float*)alloc(3 * EE * 4);
    float* biasc  = (float*)alloc(3 * EE * 4);
    float* pooled = (float*)alloc((size_t)BB * EE * 4);
    // aliases
    unsigned short* Ab  = (unsigned short*)qkv;
    unsigned short* A2b = (unsigned short*)cqkv;
    float* tm = qkv;
    float* tc = cqkv;
    unsigned short* ctxm = ctx2;
    unsigned short* ctxc = ctx2 + (size_t)MPAD * EE;

    dim3 t256(256);

    // ---- patch embed ----
    cvt_kernel<<<dim3(589824 / 4 / 256), t256, 0, stream>>>(patch_w, pw_m, 589824);
    cvt_kernel<<<dim3(589824 / 4 / 256), t256, 0, stream>>>(cpatch_w, pw_c, 589824);
    im2col_kernel<<<dim3((PROWS * EE + 255) / 256), t256, 0, stream>>>(x, colb);
    mfma_gemm2<<<dim3(EE / 128, 2 * HTILES), t256, 0, stream>>>(
        colb, colb, pw_m, pw_c, patch_b, cpatch_b, EE, EE, MODE_F32, MODE_F32,
        nullptr, nullptr, nullptr, tm, tc, nullptr, nullptr);
    assemble_kernel<<<dim3((NROWS * EE + 255) / 256), t256, 0, stream>>>(
        tm, tc, cls_tok, ccls_tok, xm, xc);

    dim3 gridQKV(3 * EE / 128, 2 * HTILES);
    dim3 gridE(EE / 128, 2 * HTILES);
    dim3 gridMLP(MLPD / 128, 2 * HTILES);
    dim3 gridPre(4, NBH);
    dim3 gridWass(2, 2, NBH);
    dim3 gridSm((NBH * NN + 3) / 4);
    dim3 gridCtx(2, NBH);
    dim3 gridCvtL((W_TOTAL / 4 + 255) / 256);
    dim3 gridLN(2 * NROWS);
    const unsigned short* xn2c = xn2 + (size_t)MPAD * EE;
    const unsigned short* hbufc = hbuf + (size_t)MPAD * MLPD;

    for (int l = 0; l < LL; l++) {
        cvt_layer_kernel<<<gridCvtL, t256, 0, stream>>>(
            qkv_w + (size_t)l * 3 * EE * EE, proj_w + (size_t)l * EE * EE,
            cproj_w + (size_t)l * EE * EE, fc1_w + (size_t)l * MLPD * EE,
            fc2_w + (size_t)l * EE * MLPD, wbuf);
        qkvbias_kernel<<<dim3(9), t256, 0, stream>>>(
            q_bias + l * EE, v_bias + l * EE, cq_bias + l * EE, cv_bias + l * EE,
            biasq, biasc);

        // norm1 (both streams) + qkv dual GEMM
        ln2_kernel<<<gridLN, t256, 0, stream>>>(xm, xc, xn2, norm1_g + l * EE, norm1_b + l * EE);
        mfma_gemm2<<<gridQKV, t256, 0, stream>>>(
            xn2, xn2c, wbuf + W_QKV, wbuf + W_QKV, biasq, biasc, EE, 3 * EE,
            MODE_F32, MODE_ELU1F, nullptr, nullptr, nullptr, qkv, cqkv, nullptr, nullptr);

        // attention
        pre_kernel<<<gridPre, t256, 0, stream>>>(qkv, cqkv, Aq, Bk, rsum, csum, vT, cvT);
        wass_gemm<<<gridWass, t256, 0, stream>>>(Aq, Bk, rsum, csum, rpb, S);
        softmax_kernel<<<gridSm, t256, 0, stream>>>(S, Ab, A2b);
        ctx_gemm<<<gridCtx, t256, 0, stream>>>(Ab, A2b, vT, cvT, ctxm, ctxc);

        // proj dual (different weights per half) + residual
        mfma_gemm2<<<gridE, t256, 0, stream>>>(
            ctxm, ctxc, wbuf + W_PROJ, wbuf + W_CPROJ, proj_b + l * EE, cproj_b + l * EE,
            EE, EE, MODE_RESF, MODE_RESF, gamma1 + l * EE, xm, xc, xm, xc, nullptr, nullptr);

        // norm2 + MLP dual
        ln2_kernel<<<gridLN, t256, 0, stream>>>(xm, xc, xn2, norm2_g + l * EE, norm2_b + l * EE);
        mfma_gemm2<<<gridMLP, t256, 0, stream>>>(
            xn2, xn2c, wbuf + W_FC1, wbuf + W_FC1, fc1_b + l * MLPD, fc1_b + l * MLPD,
            EE, MLPD, MODE_GELUB, MODE_GELUB, nullptr, nullptr, nullptr,
            nullptr, nullptr, hbuf, hbuf + (size_t)MPAD * MLPD);
        mfma_gemm2<<<gridE, t256, 0, stream>>>(
            hbuf, hbufc, wbuf + W_FC2, wbuf + W_FC2, fc2_b + l * EE, fc2_b + l * EE,
            MLPD, EE, MODE_RESF, MODE_RESF, gamma2 + l * EE, xm, xc, xm, xc, nullptr, nullptr);
    }

    // ---- head ----
    pool_ln_kernel<<<dim3(BB), t256, 0, stream>>>(xm, pooled, fcn_g, fcn_b);
    {
        dim3 grid((NCLS + 63) / 64, (BB + 63) / 64);
        gemm_kernel<<<grid, t256, 0, stream>>>(pooled, head_w, head_b, out, BB, NCLS, EE);
    }
}